// Round 5
// baseline (1163.190 us; speedup 1.0000x reference)
//
#include <hip/hip_runtime.h>
#include <hip/hip_bf16.h>
#include <math.h>

typedef __hip_bfloat16 bf16;

#define B_ 16
#define L_ 2048
#define DM 256
#define DI 512
#define NH 8
#define HD 64
#define DS 64
#define CD 640
#define DIP 1160
#define XB 648
#define NP 1280
#define NL 4
#define Q_ 64
#define NCH 32
#define MROWS (B_*L_)
#define EPS_ 1e-5f
#define NIN 17
#define NSMALL 14
#define STGOFF 32
#define WIPT 28552
#define WOPT 683912
#define HMPOFF 946056
#define SLICEOFF 1011592
#define PERROW 2004

__device__ __forceinline__ float u2f(unsigned short u){ return __uint_as_float(((unsigned)u)<<16); }
__device__ __forceinline__ unsigned short f2bu(float f){ bf16 h = __float2bfloat16(f); return *(unsigned short*)&h; }
__device__ __forceinline__ float sigmoidf_(float x){ return 1.f/(1.f+__expf(-x)); }
__device__ __forceinline__ float siluf_(float x){ return x*sigmoidf_(x); }
__device__ __forceinline__ float softplusf_(float x){ return (x>20.f)? x : log1pf(__expf(x)); }

typedef __attribute__((ext_vector_type(8))) short short8v;
typedef __attribute__((ext_vector_type(4))) float float4v;

__device__ __forceinline__ void gl_lds16(const unsigned short* g, unsigned short* l){
    __builtin_amdgcn_global_load_lds(
        (const __attribute__((address_space(1))) unsigned int*)g,
        (__attribute__((address_space(3))) unsigned int*)l,
        16, 0, 0);
}

__device__ const int kN17[NIN] = {1507328,11776,256,1187840,10240,2560,32,32,32,2048,524288,256,256,256,1,768,3};
__device__ const int sIdx[NSMALL] = {1,2,4,5,6,7,8,9,11,12,13,14,15,16};
__device__ const int sNum[NSMALL] = {11776,256,10240,2560,32,32,32,2048,256,256,256,1,768,3};
__device__ const int sOff[NSMALL] = {0,11776,12032,22272,24832,24864,24896,24928,26976,27232,27488,27744,27748,28516};

struct PtrTab { const void* p[NIN]; };

__global__ __launch_bounds__(64) void k_sentinel(float* out, float v){
    int t = threadIdx.x;
    out[t] = (t==0) ? v : 0.f;
}

__global__ __launch_bounds__(256) void k_detect(PtrTab t, int* flags){
    int i = blockIdx.x;
    int n = kN17[i];
    int S = n < 4096 ? n : 4096;
    const unsigned short* u = (const unsigned short*)t.p[i];
    __shared__ int big, ze, zo, so;
    if (threadIdx.x == 0){ big=0; ze=0; zo=0; so=0; }
    __syncthreads();
    int lbig=0, lze=0, lzo=0, lso=0;
    for (int j=threadIdx.x; j<S; j+=256){
        unsigned short v = u[j];
        int e = (v>>7)&0xFF;
        if (e >= 131) lbig = 1;
        int isz = ((v & 0x7FFF) == 0) ? 1 : 0;
        if (j & 1){ lso++; lzo += isz; } else { lze += isz; }
    }
    if (lbig) atomicOr(&big, 1);
    atomicAdd(&ze, lze); atomicAdd(&zo, lzo); atomicAdd(&so, lso);
    __syncthreads();
    if (threadIdx.x == 0){
        int Se = S - so;
        flags[i] = (big || (so > 0 && 4*ze >= 3*Se && 4*zo <= so)) ? 1 : 0;
    }
}

__global__ __launch_bounds__(256) void k_stage(PtrTab t, const int* __restrict__ flags,
                                               float* __restrict__ stg){
    int a = blockIdx.y;
    int idx = sIdx[a];
    int n = sNum[a];
    float* dst = stg + sOff[a];
    const void* p = t.p[idx];
    if (flags[idx]){
        const float* s = (const float*)p;
        for (int j=blockIdx.x*256+threadIdx.x; j<n; j += gridDim.x*256) dst[j] = s[j];
    } else {
        const unsigned short* s = (const unsigned short*)p;
        for (int j=blockIdx.x*256+threadIdx.x; j<n; j += gridDim.x*256) dst[j] = u2f(s[j]);
    }
}

__global__ __launch_bounds__(256) void k_wip(const void* __restrict__ src,
                                             const int* __restrict__ flag,
                                             unsigned short* __restrict__ dst){
    int n = blockIdx.x, l = blockIdx.y, k = threadIdx.x;
    unsigned short b = 0;
    if (n < DIP){
        size_t si = ((size_t)l*DM + k)*DIP + n;
        if (flag[0]) b = f2bu(((const float*)src)[si]);
        else         b = ((const unsigned short*)src)[si];
    }
    dst[((size_t)l*NP + n)*DM + k] = b;
}

__global__ __launch_bounds__(256) void k_wop(const void* __restrict__ src,
                                             const int* __restrict__ flag,
                                             unsigned short* __restrict__ dst){
    int n = blockIdx.x, l = blockIdx.y;
    for (int k = threadIdx.x; k < DI; k += 256){
        size_t si = ((size_t)l*DI + k)*DM + n;
        unsigned short b;
        if (flag[0]) b = f2bu(((const float*)src)[si]);
        else         b = ((const unsigned short*)src)[si];
        dst[((size_t)l*DM + n)*DI + k] = b;
    }
}

__device__ __forceinline__ float blockSum256(float v, float* red){
    #pragma unroll
    for (int off=32; off>0; off>>=1) v += __shfl_down(v, off);
    if ((threadIdx.x & 63) == 0) red[threadIdx.x >> 6] = v;
    __syncthreads();
    float s = red[0] + red[1] + red[2] + red[3];
    __syncthreads();
    return s;
}

// ------- inproj: 32 rows per block; w read once per block, reused 32x -------
__global__ __launch_bounds__(256) void k_inproj(const void* __restrict__ x,
                                                const int* __restrict__ flags,
                                                size_t xoff,
                                                const float* __restrict__ w,
                                                const float* __restrict__ bias,
                                                float* __restrict__ h,
                                                unsigned short* __restrict__ hbf){
    __shared__ float xs[32*46];
    int row0 = blockIdx.x*32;
    int t = threadIdx.x;
    bool f32 = flags[0] != 0;
    for (int j = t; j < 32*46; j += 256){
        size_t gi = xoff + (size_t)row0*46 + j;
        xs[j] = f32 ? ((const float*)x)[gi] : u2f(((const unsigned short*)x)[gi]);
    }
    __syncthreads();
    float bv = bias[t];
    float acc[32];
    #pragma unroll
    for (int r=0;r<32;r++) acc[r] = bv;
    for (int k=0;k<46;k++){
        float wv = w[k*DM + t];
        #pragma unroll
        for (int r=0;r<32;r++) acc[r] += xs[r*46 + k]*wv;
    }
    #pragma unroll
    for (int r=0;r<32;r++){
        size_t o = (size_t)(row0 + r)*DM + t;
        h[o] = acc[r];
        hbf[o] = f2bu(acc[r]);
    }
}

// ------- mgemm: tri-buffered global_load_lds pipeline with COUNTED vmcnt -------
// Per K-step: issue next-tile loads, s_waitcnt vmcnt(4) (keeps new loads in
// flight, waits only for current tile), raw s_barrier, compute. Triple buffer
// makes the WAR hazard safe: stage into buf[(t+1)%3] happens after barrier
// t-1, which follows every wave's compute of t-2 (last reader of that buf).
template<int MODE>
__global__ __launch_bounds__(256) void k_mgemm(const unsigned short* __restrict__ A,
                                               const unsigned short* __restrict__ Bt,
                                               float* __restrict__ O1,
                                               unsigned short* __restrict__ O1b,
                                               unsigned short* __restrict__ O2b,
                                               unsigned short* __restrict__ O3,
                                               int K){
    __shared__ unsigned short As[3][4096];
    __shared__ unsigned short Bs[3][4096];
    int tid = threadIdx.x;
    int wave = tid >> 6, lane = tid & 63, quad = lane >> 4, l15 = lane & 15;
    // XCD-aware bijective swizzle (nwg%8==0 for all grids here).
    int p = blockIdx.y * gridDim.x + blockIdx.x;
    int nwg = gridDim.x * gridDim.y;
    int cpx = nwg >> 3;
    int logical = (p & 7) * cpx + (p >> 3);
    int by = logical / gridDim.x;
    int bx = logical - by * gridDim.x;
    int mbase = by*128, nbase = bx*128;
    int wm = (wave & 1)*64, wn = (wave >> 1)*64;
    float4v zero4 = {0.f,0.f,0.f,0.f};
    float4v acc[4][4];
    #pragma unroll
    for (int mi=0;mi<4;mi++)
        #pragma unroll
        for (int ni=0;ni<4;ni++) acc[mi][ni] = zero4;

    int nt = K >> 5;
    int lbase0 = (wave*64)*8;        // f-base for chunk i=0 (shorts)
    int lbase1 = (256 + wave*64)*8;  // f-base for chunk i=1
    int kc0 = tid >> 7;              // chunk 0: f = tid  -> kc in {0,1}
    int kc1 = kc0 + 2;               // chunk 1: f = 256+tid -> kc in {2,3}
    const unsigned short* Arow0 = A + (size_t)(mbase+(tid&127))*K;
    const unsigned short* Brow0 = Bt + (size_t)(nbase+(tid&127))*K;

    // prologue: stage tile 0 into buf 0
    gl_lds16(Arow0 + kc0*8, &As[0][lbase0]);
    gl_lds16(Brow0 + kc0*8, &Bs[0][lbase0]);
    gl_lds16(Arow0 + kc1*8, &As[0][lbase1]);
    gl_lds16(Brow0 + kc1*8, &Bs[0][lbase1]);

    int cur = 0;
    for (int t = 0; t < nt; ++t){
        int nxt = (cur == 2) ? 0 : cur + 1;
        if (t+1 < nt){
            int ko = (t+1)*32;
            gl_lds16(Arow0 + ko + kc0*8, &As[nxt][lbase0]);
            gl_lds16(Brow0 + ko + kc0*8, &Bs[nxt][lbase0]);
            gl_lds16(Arow0 + ko + kc1*8, &As[nxt][lbase1]);
            gl_lds16(Brow0 + ko + kc1*8, &Bs[nxt][lbase1]);
            asm volatile("s_waitcnt vmcnt(4)" ::: "memory");
        } else {
            asm volatile("s_waitcnt vmcnt(0)" ::: "memory");
        }
        __builtin_amdgcn_s_barrier();
        __builtin_amdgcn_sched_barrier(0);
        const unsigned short* Ac = &As[cur][0];
        const unsigned short* Bc = &Bs[cur][0];
        short8v af[4], bfr[4];
        #pragma unroll
        for (int mi=0;mi<4;mi++) af[mi] = *(const short8v*)&Ac[(quad*128 + wm + mi*16 + l15)*8];
        #pragma unroll
        for (int ni=0;ni<4;ni++) bfr[ni] = *(const short8v*)&Bc[(quad*128 + wn + ni*16 + l15)*8];
        #pragma unroll
        for (int mi=0;mi<4;mi++)
            #pragma unroll
            for (int ni=0;ni<4;ni++)
                acc[mi][ni] = __builtin_amdgcn_mfma_f32_16x16x32_bf16(af[mi], bfr[ni], acc[mi][ni], 0, 0, 0);
        cur = nxt;
    }
    #pragma unroll
    for (int mi=0;mi<4;mi++){
        #pragma unroll
        for (int ni=0;ni<4;ni++){
            int col = nbase + wn + ni*16 + l15;
            #pragma unroll
            for (int reg=0;reg<4;reg++){
                int grow = mbase + wm + mi*16 + quad*4 + reg;
                float v = acc[mi][ni][reg];
                if (MODE == 0){
                    if (col < DI) O1b[(size_t)grow*DI + col] = f2bu(v);
                    else if (col < DIP) O2b[(size_t)grow*XB + (col - DI)] = f2bu(v);
                } else {
                    float hnew = O1[(size_t)grow*DM + col] + v;
                    O1[(size_t)grow*DM + col] = hnew;
                    O3[(size_t)grow*DM + col] = f2bu(hnew);
                }
            }
        }
    }
}

// ------- one-pass depthwise conv + SiLU over all CD channels -> cvb -------
__global__ __launch_bounds__(256) void k_conv(const unsigned short* __restrict__ xbb,
                                              const float* __restrict__ cw,
                                              const float* __restrict__ cb,
                                              unsigned short* __restrict__ cvb){
    int tid = threadIdx.x;
    int c0 = (blockIdx.x*16 + (tid & 15))*4;
    int r0 = blockIdx.y*64 + (tid >> 4);
    float wA[4], wB[4], wC[4], wD[4];
    {
        float4 t0 = *(const float4*)&cw[(size_t)(c0+0)*4];
        float4 t1 = *(const float4*)&cw[(size_t)(c0+1)*4];
        float4 t2 = *(const float4*)&cw[(size_t)(c0+2)*4];
        float4 t3 = *(const float4*)&cw[(size_t)(c0+3)*4];
        wA[0]=t0.x; wA[1]=t0.y; wA[2]=t0.z; wA[3]=t0.w;
        wB[0]=t1.x; wB[1]=t1.y; wB[2]=t1.z; wB[3]=t1.w;
        wC[0]=t2.x; wC[1]=t2.y; wC[2]=t2.z; wC[3]=t2.w;
        wD[0]=t3.x; wD[1]=t3.y; wD[2]=t3.z; wD[3]=t3.w;
    }
    float4 bb = *(const float4*)&cb[c0];
    #pragma unroll
    for (int i=0;i<4;i++){
        int r = r0 + i*16;
        int l = r & (L_-1);
        float a0=bb.x, a1=bb.y, a2=bb.z, a3=bb.w;
        #pragma unroll
        for (int j=0;j<4;j++){
            if (l-3+j >= 0){
                ushort4 uv = *(const ushort4*)&xbb[(size_t)(r-3+j)*XB + c0];
                a0 += u2f(uv.x)*wA[j];
                a1 += u2f(uv.y)*wB[j];
                a2 += u2f(uv.z)*wC[j];
                a3 += u2f(uv.w)*wD[j];
            }
        }
        ushort4 ov;
        ov.x = f2bu(siluf_(a0));
        ov.y = f2bu(siluf_(a1));
        ov.z = f2bu(siluf_(a2));
        ov.w = f2bu(siluf_(a3));
        *(ushort4*)&cvb[(size_t)r*CD + c0] = ov;
    }
}

__global__ __launch_bounds__(64) void k_dtcum(const unsigned short* __restrict__ xb,
                                              const float* __restrict__ dtb,
                                              const float* __restrict__ alog,
                                              float* __restrict__ dto,
                                              float* __restrict__ cumo){
    int kk = blockIdx.x, h = blockIdx.y, b = blockIdx.z;
    int t = threadIdx.x;
    int l = kk*Q_ + t;
    float raw = u2f(xb[(size_t)(b*L_ + l)*XB + CD + h]);
    float dtv = softplusf_(raw + dtb[h]);
    float A = -__expf(alog[h]);
    float s = dtv * A;
    #pragma unroll
    for (int off=1; off<64; off<<=1){
        float u = __shfl_up(s, off);
        if (t >= off) s += u;
    }
    int base = (b*NH + h)*L_ + l;
    dto[base] = dtv;
    cumo[base] = s;
}

// Group-local remap: the 8 h-blocks of one (kk,b) group all get p%8==g%8,
// i.e. the same XCD -> the shared B/C tile is fetched into that L2 once.
__device__ __forceinline__ void grp_map(int p, int &kk, int &h, int &b){
    int c = p & 7, i = p >> 3;
    h = i & 7;
    int g = (i & ~7) | c;
    kk = g & (NCH-1);
    b = g >> 5;
}

// ------- passS: reads precomputed conv output (cvb) -------
__global__ __launch_bounds__(256) void k_passS(const unsigned short* __restrict__ cvb,
                                               const float* __restrict__ dt,
                                               const float* __restrict__ cum,
                                               float* __restrict__ S){
    __shared__ unsigned short Bw[64*72];
    __shared__ unsigned short Xt[64*72];
    __shared__ float sw[64];
    int kk, h, b;
    grp_map(blockIdx.x, kk, h, b);
    int tid = threadIdx.x;
    int bh = b*NH + h;
    int l0 = kk*Q_;
    if (tid < 64){
        int base = bh*L_ + l0;
        float c = cum[base + tid];
        float c63 = cum[base + 63];
        sw[tid] = dt[base + tid]*__expf(fminf(c63 - c, 0.f));
    }
    __syncthreads();
    int srow = tid >> 4, c0 = (tid & 15)*4;
    #pragma unroll
    for (int i=0;i<4;i++){
        int s = srow + i*16;
        size_t rb = ((size_t)(b*L_ + l0 + s))*CD;
        ushort4 bv = *(const ushort4*)&cvb[rb + DI + c0];
        ushort4 xv = *(const ushort4*)&cvb[rb + h*HD + c0];
        float w = sw[s];
        Bw[(c0+0)*72 + s] = f2bu(w*u2f(bv.x));
        Bw[(c0+1)*72 + s] = f2bu(w*u2f(bv.y));
        Bw[(c0+2)*72 + s] = f2bu(w*u2f(bv.z));
        Bw[(c0+3)*72 + s] = f2bu(w*u2f(bv.w));
        Xt[(c0+0)*72 + s] = xv.x;
        Xt[(c0+1)*72 + s] = xv.y;
        Xt[(c0+2)*72 + s] = xv.z;
        Xt[(c0+3)*72 + s] = xv.w;
    }
    __syncthreads();
    int wave = tid >> 6, lane = tid & 63, quad = lane >> 4, l15 = lane & 15;
    int wn = (wave & 1)*32, wp = (wave >> 1)*32;
    float4v zero4 = {0.f,0.f,0.f,0.f};
    float4v acc[2][2];
    #pragma unroll
    for (int mi=0;mi<2;mi++)
        #pragma unroll
        for (int ni=0;ni<2;ni++) acc[mi][ni] = zero4;
    #pragma unroll
    for (int k0=0;k0<64;k0+=32){
        short8v af[2], bfr[2];
        #pragma unroll
        for (int mi=0;mi<2;mi++) af[mi] = *(const short8v*)&Bw[(wn + mi*16 + l15)*72 + k0 + quad*8];
        #pragma unroll
        for (int ni=0;ni<2;ni++) bfr[ni] = *(const short8v*)&Xt[(wp + ni*16 + l15)*72 + k0 + quad*8];
        #pragma unroll
        for (int mi=0;mi<2;mi++)
            #pragma unroll
            for (int ni=0;ni<2;ni++)
                acc[mi][ni] = __builtin_amdgcn_mfma_f32_16x16x32_bf16(af[mi], bfr[ni], acc[mi][ni], 0, 0, 0);
    }
    size_t Sbase = ((size_t)bh*NCH + kk)*4096;
    #pragma unroll
    for (int mi=0;mi<2;mi++){
        #pragma unroll
        for (int ni=0;ni<2;ni++){
            int p = wp + ni*16 + l15;
            #pragma unroll
            for (int reg=0;reg<4;reg++){
                int n = wn + mi*16 + quad*4 + reg;
                S[Sbase + n*64 + p] = acc[mi][ni][reg];
            }
        }
    }
}

// ------- combine: 4-way split over the p dimension (grid.z) -------
__global__ __launch_bounds__(256) void k_combine(const float* __restrict__ cum,
                                                 float* __restrict__ S){
    int h = blockIdx.x, b = blockIdx.y, z = blockIdx.z;
    int bh = b*NH + h;
    int tid = threadIdx.x;
    float4 st = make_float4(0.f,0.f,0.f,0.f);
    size_t base0 = ((size_t)bh*NCH)*4096 + (size_t)z*1024 + (size_t)tid*4;
    for (int k=0;k<NCH;k++){
        size_t base = base0 + (size_t)k*4096;
        float dk = __expf(fminf(cum[bh*L_ + k*Q_ + 63], 0.f));
        float4 a = *(const float4*)&S[base];
        *(float4*)&S[base] = st;
        st.x = a.x + dk*st.x;
        st.y = a.y + dk*st.y;
        st.z = a.z + dk*st.z;
        st.w = a.w + dk*st.w;
    }
}

// ------- finalize2: reads precomputed conv output (cvb); Ml aliases Bs -------
__global__ __launch_bounds__(256) void k_finalize2(const unsigned short* __restrict__ cvb,
                                                   const float* __restrict__ dt,
                                                   const float* __restrict__ cum,
                                                   const float* __restrict__ Dp,
                                                   const float* __restrict__ S,
                                                   unsigned short* __restrict__ yB){
    __shared__ unsigned short Ct[64*72];
    __shared__ unsigned short Bs[64*72];   // aliased as Ml after GEMM1
    __shared__ unsigned short Xt[64*72];
    __shared__ unsigned short St[64*72];
    __shared__ float sdt[64], scum[64];
    unsigned short* const Ml = &Bs[0];
    int kk, h, b;
    grp_map(blockIdx.x, kk, h, b);
    int tid = threadIdx.x;
    int bh = b*NH + h;
    int l0 = kk*Q_;
    if (tid < 64){
        int base = bh*L_ + l0;
        sdt[tid] = dt[base + tid];
        scum[tid] = cum[base + tid];
    }
    int rr = tid >> 4, c0 = (tid & 15)*4;
    size_t Sbase = ((size_t)bh*NCH + kk)*4096;
    #pragma unroll
    for (int i=0;i<4;i++){
        int r = rr + i*16;
        size_t rb = ((size_t)(b*L_ + l0 + r))*CD;
        *(ushort4*)&Ct[r*72 + c0] = *(const ushort4*)&cvb[rb + DI + DS + c0];
        *(ushort4*)&Bs[r*72 + c0] = *(const ushort4*)&cvb[rb + DI + c0];
        ushort4 xv = *(const ushort4*)&cvb[rb + h*HD + c0];
        Xt[(c0+0)*72 + r] = xv.x;
        Xt[(c0+1)*72 + r] = xv.y;
        Xt[(c0+2)*72 + r] = xv.z;
        Xt[(c0+3)*72 + r] = xv.w;
        float4 sv = *(const float4*)&S[Sbase + r*64 + c0];
        St[(c0+0)*72 + r] = f2bu(sv.x);
        St[(c0+1)*72 + r] = f2bu(sv.y);
        St[(c0+2)*72 + r] = f2bu(sv.z);
        St[(c0+3)*72 + r] = f2bu(sv.w);
    }
    __syncthreads();
    int wave = tid >> 6, lane = tid & 63, quad = lane >> 4, l15 = lane & 15;
    int wt2 = (wave & 1)*32, wc = (wave >> 1)*32;
    float4v zero4 = {0.f,0.f,0.f,0.f};
    {
        float4v acc[2][2];
        #pragma unroll
        for (int mi=0;mi<2;mi++)
            #pragma unroll
            for (int ni=0;ni<2;ni++) acc[mi][ni] = zero4;
        #pragma unroll
        for (int k0=0;k0<64;k0+=32){
            short8v af[2], bfr[2];
            #pragma unroll
            for (int mi=0;mi<2;mi++) af[mi] = *(const short8v*)&Ct[(wt2 + mi*16 + l15)*72 + k0 + quad*8];
            #pragma unroll
            for (int ni=0;ni<2;ni++) bfr[ni] = *(const short8v*)&Bs[(wc + ni*16 + l15)*72 + k0 + quad*8];
            #pragma unroll
            for (int mi=0;mi<2;mi++)
                #pragma unroll
                for (int ni=0;ni<2;ni++)
                    acc[mi][ni] = __builtin_amdgcn_mfma_f32_16x16x32_bf16(af[mi], bfr[ni], acc[mi][ni], 0, 0, 0);
        }
        __syncthreads();   // all waves done reading Bs before it becomes Ml
        #pragma unroll
        for (int mi=0;mi<2;mi++){
            #pragma unroll
            for (int ni=0;ni<2;ni++){
                int s = wc + ni*16 + l15;
                #pragma unroll
                for (int reg=0;reg<4;reg++){
                    int t = wt2 + mi*16 + quad*4 + reg;
                    float m = (s <= t) ? acc[mi][ni][reg]*sdt[s]*__expf(fminf(scum[t]-scum[s], 0.f)) : 0.f;
                    Ml[t*72 + s] = f2bu(m);
                }
            }
        }
    }
    __syncthreads();
    {
        float4v a1[2][2], a2[2][2];
        #pragma unroll
        for (int mi=0;mi<2;mi++)
            #pragma unroll
            for (int ni=0;ni<2;ni++){ a1[mi][ni] = zero4; a2[mi][ni] = zero4; }
        #pragma unroll
        for (int k0=0;k0<64;k0+=32){
            short8v mf[2], cf[2], xf[2], sf[2];
            #pragma unroll
            for (int mi=0;mi<2;mi++){
                mf[mi] = *(const short8v*)&Ml[(wt2 + mi*16 + l15)*72 + k0 + quad*8];
                cf[mi] = *(const short8v*)&Ct[(wt2 + mi*16 + l15)*72 + k0 + quad*8];
            }
            #pragma unroll
            for (int ni=0;ni<2;ni++){
                xf[ni] = *(const short8v*)&Xt[(wc + ni*16 + l15)*72 + k0 + quad*8];
                sf[ni] = *(const short8v*)&St[(wc + ni*16 + l15)*72 + k0 + quad*8];
            }
            #pragma unroll
            for (int mi=0;mi<2;mi++)
                #pragma unroll
                for (int ni=0;ni<2;ni++){
                    a1[mi][ni] = __builtin_amdgcn_mfma_f32_16x16x32_bf16(mf[mi], xf[ni], a1[mi][ni], 0, 0, 0);
                    a2[mi][ni] = __builtin_amdgcn_mfma_f32_16x16x32_bf16(cf[mi], sf[ni], a2[mi][ni], 0, 0, 0);
                }
        }
        float Dh = Dp[h];
        #pragma unroll
        for (int mi=0;mi<2;mi++){
            #pragma unroll
            for (int ni=0;ni<2;ni++){
                int p = wc + ni*16 + l15;
                #pragma unroll
                for (int reg=0;reg<4;reg++){
                    int t = wt2 + mi*16 + quad*4 + reg;
                    float e = __expf(fminf(scum[t], 0.f));
                    float xval = u2f(Xt[p*72 + t]);
                    yB[(size_t)(b*L_ + l0 + t)*DI + h*HD + p] =
                        f2bu(a1[mi][ni][reg] + e*a2[mi][ni][reg] + Dh*xval);
                }
            }
        }
    }
}

__global__ __launch_bounds__(256) void k_gaterms(const unsigned short* __restrict__ z,
                                                 const float* __restrict__ rw,
                                                 const unsigned short* __restrict__ yB,
                                                 unsigned short* __restrict__ ybf){
    __shared__ float red[4];
    int row = blockIdx.x;
    int tid = threadIdx.x;
    float g[2]; float ss = 0.f;
    #pragma unroll
    for (int r=0;r<2;r++){
        int d = tid + r*256;
        float zv = u2f(z[(size_t)row*DI + d]);
        float yv = u2f(yB[(size_t)row*DI + d]);
        float gv = yv * siluf_(zv);
        g[r] = gv;
        ss += gv*gv;
    }
    float tot = blockSum256(ss, red);
    float rinv = rsqrtf(tot*(1.f/512.f) + EPS_);
    #pragma unroll
    for (int r=0;r<2;r++){
        int d = tid + r*256;
        ybf[(size_t)row*DI + d] = f2bu(g[r]*rinv*rw[d]);
    }
}

__global__ __launch_bounds__(256) void k_ln(const float* __restrict__ h,
                                            const float* __restrict__ lw,
                                            const float* __restrict__ lb,
                                            float* __restrict__ out){
    __shared__ float red[4];
    int row = blockIdx.x;
    int tid = threadIdx.x;
    float v = h[(size_t)row*DM + tid];
    float mu = blockSum256(v, red)*(1.f/256.f);
    float d = v - mu;
    float var = blockSum256(d*d, red)*(1.f/256.f);
    out[(size_t)row*DM + tid] = d*rsqrtf(var + EPS_)*lw[tid] + lb[tid];
}

__global__ __launch_bounds__(256) void k_meanl(const float* __restrict__ ln,
                                               float* __restrict__ hmp,
                                               int b0){
    int g = blockIdx.x, bl = blockIdx.y;
    int tid = threadIdx.x;
    float s = 0.f;
    for (int i=0;i<128;i++){
        int l = g*128 + i;
        s += ln[(size_t)(bl*L_ + l)*DM + tid];
    }
    hmp[((size_t)(b0+bl)*16 + g)*DM + tid] = s*(1.f/2048.f);
}

__global__ __launch_bounds__(256) void k_heads(const float* __restrict__ hmp,
                                               const float* __restrict__ dw,
                                               const float* __restrict__ db,
                                               const float* __restrict__ rw,
                                               const float* __restrict__ rb,
                                               float* __restrict__ out){
    __shared__ float red[4];
    int b = blockIdx.x;
    int tid = threadIdx.x;
    float hv = 0.f;
    #pragma unroll
    for (int g=0; g<16; g++) hv += hmp[((size_t)b*16 + g)*DM + tid];
    float s0 = hv*dw[tid];
    float s1 = hv*rw[tid*3+0];
    float s2 = hv*rw[tid*3+1];
    float s3 = hv*rw[tid*3+2];
    s0 = blockSum256(s0, red);
    s1 = blockSum256(s1, red);
    s2 = blockSum256(s2, red);
    s3 = blockSum256(s3, red);
    if (tid == 0){
        out[b] = s0 + db[0];
        out[16 + b*3 + 0] = s1 + rb[0];
        out[16 + b*3 + 1] = s2 + rb[1];
        out[16 + b*3 + 2] = s3 + rb[2];
    }
}

extern "C" void kernel_launch(void* const* d_in, const int* in_sizes, int n_in,
                              void* d_out, int out_size, void* d_ws, size_t ws_size,
                              hipStream_t stream){
    static const int expSizes[NIN] = {1507328,11776,256,1187840,10240,2560,32,32,32,2048,524288,256,256,256,1,768,3};
    float* out = (float*)d_out;

    if (n_in != NIN){
        k_sentinel<<<1,64,0,stream>>>(out, 9.0e6f);
        return;
    }
    for (int i=0;i<NIN;i++){
        if (in_sizes[i] != expSizes[i]){
            k_sentinel<<<1,64,0,stream>>>(out, (float)(i+1)*1.0e5f);
            return;
        }
    }
    size_t need16 = ((size_t)SLICEOFF + 2048ull*PERROW)*4ull;
    if (ws_size < need16){
        float mb = (float)(ws_size >> 20);
        k_sentinel<<<1,64,0,stream>>>(out, 2.0e7f + mb*131072.f);
        return;
    }

    float* ws = (float*)d_ws;
    int* flags = (int*)d_ws;
    float* stg = ws + STGOFF;
    unsigned short* ipwT = (unsigned short*)(ws + WIPT);
    unsigned short* opwT = (unsigned short*)(ws + WOPT);
    float* hmp = ws + HMPOFF;

    PtrTab pt;
    for (int i=0;i<NIN;i++) pt.p[i] = d_in[i];

    k_detect<<<NIN, 256, 0, stream>>>(pt, flags);
    k_stage<<<dim3(8, NSMALL), 256, 0, stream>>>(pt, flags, stg);
    k_wip<<<dim3(NP, NL), 256, 0, stream>>>(d_in[3], flags+3, ipwT);
    k_wop<<<dim3(DM, NL), 256, 0, stream>>>(d_in[10], flags+10, opwT);

    const float* inp_w = stg + 0;
    const float* inp_b = stg + 11776;
    const float* cw    = stg + 12032;
    const float* cb    = stg + 22272;
    const float* dtb   = stg + 24832;
    const float* alog  = stg + 24864;
    const float* Dp    = stg + 24896;
    const float* rmsw  = stg + 24928;
    const float* lnw   = stg + 26976;
    const float* lnb   = stg + 27232;
    const float* dw    = stg + 27488;
    const float* db    = stg + 27744;
    const float* rw    = stg + 27748;
    const float* rb    = stg + 28516;

    int nsl = 1;
    while (((size_t)SLICEOFF + ((size_t)MROWS/nsl)*PERROW)*4ull > ws_size) nsl <<= 1;
    const size_t R = (size_t)MROWS / nsl;
    const int SB = B_ / nsl;

    float* base = ws + SLICEOFF;
    // Layout (floats-per-row offsets, lifetime-aliased):
    //   hbuf [0,256) f32 | hbf [256,384) bf16 | zb [384,640) bf16
    //   xbb  [640,964) bf16 (raw xBC+dt; dead after dtcum) -- ybB aliases [640,896)
    //   cvb  [964,1284) bf16 (conv+SiLU; dead after finalize2) -- ybf aliases [964,1220)
    //   S    [1284,1796) f32 (also LN scratch) | dt [1796,1804) | cum [1804,1812)
    float* hbuf = base;
    unsigned short* hbf  = (unsigned short*)(base + R*256);
    unsigned short* zb   = (unsigned short*)(base + R*384);
    unsigned short* xbb  = (unsigned short*)(base + R*640);
    unsigned short* ybB  = (unsigned short*)(base + R*640);   // alias: xbb dead after dtcum
    unsigned short* cvb  = (unsigned short*)(base + R*964);
    unsigned short* ybf  = (unsigned short*)(base + R*964);   // alias: cvb dead after finalize2
    float* S   = base + R*1284;
    float* dt  = base + R*1796;
    float* cum = base + R*1804;

    for (int sl=0; sl<nsl; sl++){
        k_inproj<<<(int)(R/32), 256, 0, stream>>>(d_in[0], flags, (size_t)sl*R*46, inp_w, inp_b, hbuf, hbf);
        for (int li=0; li<NL; li++){
            const float* cwl = cw + li*CD*4;
            const float* cbl = cb + li*CD;
            k_mgemm<0><<<dim3(NP/128, R/128), 256, 0, stream>>>(
                hbf, ipwT + (size_t)li*NP*DM, hbuf, zb, xbb, ybf, DM);
            k_conv<<<dim3(10, (int)(R/64)), 256, 0, stream>>>(xbb, cwl, cbl, cvb);
            k_dtcum<<<dim3(NCH,NH,SB), 64, 0, stream>>>(xbb, dtb + li*NH, alog + li*NH, dt, cum);
            k_passS<<<NCH*NH*SB, 256, 0, stream>>>(cvb, dt, cum, S);
            k_combine<<<dim3(NH,SB,4), 256, 0, stream>>>(cum, S);
            k_finalize2<<<NCH*NH*SB, 256, 0, stream>>>(cvb, dt, cum, Dp + li*NH, S, ybB);
            k_gaterms<<<(int)R, 256, 0, stream>>>(zb, rmsw + li*DI, ybB, ybf);
            k_mgemm<1><<<dim3(DM/128, R/128), 256, 0, stream>>>(
                ybf, opwT + (size_t)li*DM*DI, hbuf, zb, xbb, hbf, DI);
        }
        k_ln<<<(int)R, 256, 0, stream>>>(hbuf, lnw, lnb, S);
        k_meanl<<<dim3(16,SB), 256, 0, stream>>>(S, hmp, sl*SB);
    }
    k_heads<<<B_, 256, 0, stream>>>(hmp, dw, db, rw, rb, out);
}

// Round 6
// 1067.331 us; speedup vs baseline: 1.0898x; 1.0898x over previous
//
#include <hip/hip_runtime.h>
#include <hip/hip_bf16.h>
#include <math.h>

typedef __hip_bfloat16 bf16;

#define B_ 16
#define L_ 2048
#define DM 256
#define DI 512
#define NH 8
#define HD 64
#define DS 64
#define CD 640
#define DIP 1160
#define XB 648
#define NP 1280
#define NL 4
#define Q_ 64
#define NCH 32
#define MROWS (B_*L_)
#define EPS_ 1e-5f
#define NIN 17
#define NSMALL 14
#define STGOFF 32
#define WIPT 28552
#define WOPT 683912
#define HMPOFF 946056
#define SLICEOFF 1011592
#define PERROW 2004

__device__ __forceinline__ float u2f(unsigned short u){ return __uint_as_float(((unsigned)u)<<16); }
__device__ __forceinline__ unsigned short f2bu(float f){ bf16 h = __float2bfloat16(f); return *(unsigned short*)&h; }
__device__ __forceinline__ float sigmoidf_(float x){ return 1.f/(1.f+__expf(-x)); }
__device__ __forceinline__ float siluf_(float x){ return x*sigmoidf_(x); }
__device__ __forceinline__ float softplusf_(float x){ return (x>20.f)? x : log1pf(__expf(x)); }

typedef __attribute__((ext_vector_type(8))) short short8v;
typedef __attribute__((ext_vector_type(4))) float float4v;

__device__ const int kN17[NIN] = {1507328,11776,256,1187840,10240,2560,32,32,32,2048,524288,256,256,256,1,768,3};
__device__ const int sIdx[NSMALL] = {1,2,4,5,6,7,8,9,11,12,13,14,15,16};
__device__ const int sNum[NSMALL] = {11776,256,10240,2560,32,32,32,2048,256,256,256,1,768,3};
__device__ const int sOff[NSMALL] = {0,11776,12032,22272,24832,24864,24896,24928,26976,27232,27488,27744,27748,28516};

struct PtrTab { const void* p[NIN]; };

__global__ __launch_bounds__(64) void k_sentinel(float* out, float v){
    int t = threadIdx.x;
    out[t] = (t==0) ? v : 0.f;
}

__global__ __launch_bounds__(256) void k_detect(PtrTab t, int* flags){
    int i = blockIdx.x;
    int n = kN17[i];
    int S = n < 4096 ? n : 4096;
    const unsigned short* u = (const unsigned short*)t.p[i];
    __shared__ int big, ze, zo, so;
    if (threadIdx.x == 0){ big=0; ze=0; zo=0; so=0; }
    __syncthreads();
    int lbig=0, lze=0, lzo=0, lso=0;
    for (int j=threadIdx.x; j<S; j+=256){
        unsigned short v = u[j];
        int e = (v>>7)&0xFF;
        if (e >= 131) lbig = 1;
        int isz = ((v & 0x7FFF) == 0) ? 1 : 0;
        if (j & 1){ lso++; lzo += isz; } else { lze += isz; }
    }
    if (lbig) atomicOr(&big, 1);
    atomicAdd(&ze, lze); atomicAdd(&zo, lzo); atomicAdd(&so, lso);
    __syncthreads();
    if (threadIdx.x == 0){
        int Se = S - so;
        flags[i] = (big || (so > 0 && 4*ze >= 3*Se && 4*zo <= so)) ? 1 : 0;
    }
}

__global__ __launch_bounds__(256) void k_stage(PtrTab t, const int* __restrict__ flags,
                                               float* __restrict__ stg){
    int a = blockIdx.y;
    int idx = sIdx[a];
    int n = sNum[a];
    float* dst = stg + sOff[a];
    const void* p = t.p[idx];
    if (flags[idx]){
        const float* s = (const float*)p;
        for (int j=blockIdx.x*256+threadIdx.x; j<n; j += gridDim.x*256) dst[j] = s[j];
    } else {
        const unsigned short* s = (const unsigned short*)p;
        for (int j=blockIdx.x*256+threadIdx.x; j<n; j += gridDim.x*256) dst[j] = u2f(s[j]);
    }
}

__global__ __launch_bounds__(256) void k_wip(const void* __restrict__ src,
                                             const int* __restrict__ flag,
                                             unsigned short* __restrict__ dst){
    int n = blockIdx.x, l = blockIdx.y, k = threadIdx.x;
    unsigned short b = 0;
    if (n < DIP){
        size_t si = ((size_t)l*DM + k)*DIP + n;
        if (flag[0]) b = f2bu(((const float*)src)[si]);
        else         b = ((const unsigned short*)src)[si];
    }
    dst[((size_t)l*NP + n)*DM + k] = b;
}

__global__ __launch_bounds__(256) void k_wop(const void* __restrict__ src,
                                             const int* __restrict__ flag,
                                             unsigned short* __restrict__ dst){
    int n = blockIdx.x, l = blockIdx.y;
    for (int k = threadIdx.x; k < DI; k += 256){
        size_t si = ((size_t)l*DI + k)*DM + n;
        unsigned short b;
        if (flag[0]) b = f2bu(((const float*)src)[si]);
        else         b = ((const unsigned short*)src)[si];
        dst[((size_t)l*DM + n)*DI + k] = b;
    }
}

__device__ __forceinline__ float blockSum256(float v, float* red){
    #pragma unroll
    for (int off=32; off>0; off>>=1) v += __shfl_down(v, off);
    if ((threadIdx.x & 63) == 0) red[threadIdx.x >> 6] = v;
    __syncthreads();
    float s = red[0] + red[1] + red[2] + red[3];
    __syncthreads();
    return s;
}

// ------- inproj: 32 rows per block; w read once per block, reused 32x -------
__global__ __launch_bounds__(256) void k_inproj(const void* __restrict__ x,
                                                const int* __restrict__ flags,
                                                size_t xoff,
                                                const float* __restrict__ w,
                                                const float* __restrict__ bias,
                                                float* __restrict__ h,
                                                unsigned short* __restrict__ hbf){
    __shared__ float xs[32*46];
    int row0 = blockIdx.x*32;
    int t = threadIdx.x;
    bool f32 = flags[0] != 0;
    for (int j = t; j < 32*46; j += 256){
        size_t gi = xoff + (size_t)row0*46 + j;
        xs[j] = f32 ? ((const float*)x)[gi] : u2f(((const unsigned short*)x)[gi]);
    }
    __syncthreads();
    float bv = bias[t];
    float acc[32];
    #pragma unroll
    for (int r=0;r<32;r++) acc[r] = bv;
    for (int k=0;k<46;k++){
        float wv = w[k*DM + t];
        #pragma unroll
        for (int r=0;r<32;r++) acc[r] += xs[r*46 + k]*wv;
    }
    #pragma unroll
    for (int r=0;r<32;r++){
        size_t o = (size_t)(row0 + r)*DM + t;
        h[o] = acc[r];
        hbf[o] = f2bu(acc[r]);
    }
}

// ------- mgemm: 64x128 block tile, wave tile 32x64 (acc[2][4] = 32 AGPR),
// reg-staged LDS with 40-short padded rows (round-3 proven structure).
// Smaller accumulator keeps total regs <= 128/wave -> 4 waves/SIMD (2x TLP),
// which is what hides the 8-K-step load latency (in-wave pipelining failed
// twice: too few K-steps to build depth).
template<int MODE>
__global__ __launch_bounds__(256, 4) void k_mgemm(const unsigned short* __restrict__ A,
                                                  const unsigned short* __restrict__ Bt,
                                                  float* __restrict__ O1,
                                                  unsigned short* __restrict__ O1b,
                                                  unsigned short* __restrict__ O2b,
                                                  unsigned short* __restrict__ O3,
                                                  int K){
    __shared__ unsigned short As[64*40];
    __shared__ unsigned short Bs[128*40];
    int tid = threadIdx.x;
    int wave = tid >> 6, lane = tid & 63, quad = lane >> 4, l15 = lane & 15;
    // XCD-aware bijective swizzle (nwg%8==0 for all grids here).
    int p = blockIdx.y * gridDim.x + blockIdx.x;
    int nwg = gridDim.x * gridDim.y;
    int cpx = nwg >> 3;
    int logical = (p & 7) * cpx + (p >> 3);
    int by = logical / gridDim.x;
    int bx = logical - by * gridDim.x;
    int mbase = by*64, nbase = bx*128;
    int wm = (wave & 1)*32, wn = (wave >> 1)*64;
    float4v zero4 = {0.f,0.f,0.f,0.f};
    float4v acc[2][4];
    #pragma unroll
    for (int mi=0;mi<2;mi++)
        #pragma unroll
        for (int ni=0;ni<4;ni++) acc[mi][ni] = zero4;

    int rowA = tid >> 2, koffA = (tid & 3)*8;
    const unsigned short* Ap = A + (size_t)(mbase+rowA)*K + koffA;
    for (int k0 = 0; k0 < K; k0 += 32){
        *(uint4*)&As[rowA*40 + koffA] = *(const uint4*)&Ap[k0];
        #pragma unroll
        for (int i=0;i<2;i++){
            int c = tid + i*256;
            int row = c >> 2, koff = (c & 3)*8;
            *(uint4*)&Bs[row*40 + koff] = *(const uint4*)&Bt[(size_t)(nbase+row)*K + k0 + koff];
        }
        __syncthreads();
        short8v af[2], bfr[4];
        #pragma unroll
        for (int mi=0;mi<2;mi++) af[mi] = *(const short8v*)&As[(wm + mi*16 + l15)*40 + quad*8];
        #pragma unroll
        for (int ni=0;ni<4;ni++) bfr[ni] = *(const short8v*)&Bs[(wn + ni*16 + l15)*40 + quad*8];
        #pragma unroll
        for (int mi=0;mi<2;mi++)
            #pragma unroll
            for (int ni=0;ni<4;ni++)
                acc[mi][ni] = __builtin_amdgcn_mfma_f32_16x16x32_bf16(af[mi], bfr[ni], acc[mi][ni], 0, 0, 0);
        __syncthreads();
    }
    #pragma unroll
    for (int mi=0;mi<2;mi++){
        #pragma unroll
        for (int ni=0;ni<4;ni++){
            int col = nbase + wn + ni*16 + l15;
            #pragma unroll
            for (int reg=0;reg<4;reg++){
                int grow = mbase + wm + mi*16 + quad*4 + reg;
                float v = acc[mi][ni][reg];
                if (MODE == 0){
                    if (col < DI) O1b[(size_t)grow*DI + col] = f2bu(v);
                    else if (col < DIP) O2b[(size_t)grow*XB + (col - DI)] = f2bu(v);
                } else {
                    float hnew = O1[(size_t)grow*DM + col] + v;
                    O1[(size_t)grow*DM + col] = hnew;
                    O3[(size_t)grow*DM + col] = f2bu(hnew);
                }
            }
        }
    }
}

// ------- one-pass depthwise conv + SiLU over all CD channels -> cvb -------
__global__ __launch_bounds__(256) void k_conv(const unsigned short* __restrict__ xbb,
                                              const float* __restrict__ cw,
                                              const float* __restrict__ cb,
                                              unsigned short* __restrict__ cvb){
    int tid = threadIdx.x;
    int c0 = (blockIdx.x*16 + (tid & 15))*4;
    int r0 = blockIdx.y*64 + (tid >> 4);
    float wA[4], wB[4], wC[4], wD[4];
    {
        float4 t0 = *(const float4*)&cw[(size_t)(c0+0)*4];
        float4 t1 = *(const float4*)&cw[(size_t)(c0+1)*4];
        float4 t2 = *(const float4*)&cw[(size_t)(c0+2)*4];
        float4 t3 = *(const float4*)&cw[(size_t)(c0+3)*4];
        wA[0]=t0.x; wA[1]=t0.y; wA[2]=t0.z; wA[3]=t0.w;
        wB[0]=t1.x; wB[1]=t1.y; wB[2]=t1.z; wB[3]=t1.w;
        wC[0]=t2.x; wC[1]=t2.y; wC[2]=t2.z; wC[3]=t2.w;
        wD[0]=t3.x; wD[1]=t3.y; wD[2]=t3.z; wD[3]=t3.w;
    }
    float4 bb = *(const float4*)&cb[c0];
    #pragma unroll
    for (int i=0;i<4;i++){
        int r = r0 + i*16;
        int l = r & (L_-1);
        float a0=bb.x, a1=bb.y, a2=bb.z, a3=bb.w;
        #pragma unroll
        for (int j=0;j<4;j++){
            if (l-3+j >= 0){
                ushort4 uv = *(const ushort4*)&xbb[(size_t)(r-3+j)*XB + c0];
                a0 += u2f(uv.x)*wA[j];
                a1 += u2f(uv.y)*wB[j];
                a2 += u2f(uv.z)*wC[j];
                a3 += u2f(uv.w)*wD[j];
            }
        }
        ushort4 ov;
        ov.x = f2bu(siluf_(a0));
        ov.y = f2bu(siluf_(a1));
        ov.z = f2bu(siluf_(a2));
        ov.w = f2bu(siluf_(a3));
        *(ushort4*)&cvb[(size_t)r*CD + c0] = ov;
    }
}

__global__ __launch_bounds__(64) void k_dtcum(const unsigned short* __restrict__ xb,
                                              const float* __restrict__ dtb,
                                              const float* __restrict__ alog,
                                              float* __restrict__ dto,
                                              float* __restrict__ cumo){
    int kk = blockIdx.x, h = blockIdx.y, b = blockIdx.z;
    int t = threadIdx.x;
    int l = kk*Q_ + t;
    float raw = u2f(xb[(size_t)(b*L_ + l)*XB + CD + h]);
    float dtv = softplusf_(raw + dtb[h]);
    float A = -__expf(alog[h]);
    float s = dtv * A;
    #pragma unroll
    for (int off=1; off<64; off<<=1){
        float u = __shfl_up(s, off);
        if (t >= off) s += u;
    }
    int base = (b*NH + h)*L_ + l;
    dto[base] = dtv;
    cumo[base] = s;
}

// Group-local remap: the 8 h-blocks of one (kk,b) group all get p%8==g%8,
// i.e. the same XCD -> the shared B/C tile is fetched into that L2 once.
__device__ __forceinline__ void grp_map(int p, int &kk, int &h, int &b){
    int c = p & 7, i = p >> 3;
    h = i & 7;
    int g = (i & ~7) | c;
    kk = g & (NCH-1);
    b = g >> 5;
}

// ------- passS: reads precomputed conv output (cvb) -------
__global__ __launch_bounds__(256) void k_passS(const unsigned short* __restrict__ cvb,
                                               const float* __restrict__ dt,
                                               const float* __restrict__ cum,
                                               float* __restrict__ S){
    __shared__ unsigned short Bw[64*72];
    __shared__ unsigned short Xt[64*72];
    __shared__ float sw[64];
    int kk, h, b;
    grp_map(blockIdx.x, kk, h, b);
    int tid = threadIdx.x;
    int bh = b*NH + h;
    int l0 = kk*Q_;
    if (tid < 64){
        int base = bh*L_ + l0;
        float c = cum[base + tid];
        float c63 = cum[base + 63];
        sw[tid] = dt[base + tid]*__expf(fminf(c63 - c, 0.f));
    }
    __syncthreads();
    int srow = tid >> 4, c0 = (tid & 15)*4;
    #pragma unroll
    for (int i=0;i<4;i++){
        int s = srow + i*16;
        size_t rb = ((size_t)(b*L_ + l0 + s))*CD;
        ushort4 bv = *(const ushort4*)&cvb[rb + DI + c0];
        ushort4 xv = *(const ushort4*)&cvb[rb + h*HD + c0];
        float w = sw[s];
        Bw[(c0+0)*72 + s] = f2bu(w*u2f(bv.x));
        Bw[(c0+1)*72 + s] = f2bu(w*u2f(bv.y));
        Bw[(c0+2)*72 + s] = f2bu(w*u2f(bv.z));
        Bw[(c0+3)*72 + s] = f2bu(w*u2f(bv.w));
        Xt[(c0+0)*72 + s] = xv.x;
        Xt[(c0+1)*72 + s] = xv.y;
        Xt[(c0+2)*72 + s] = xv.z;
        Xt[(c0+3)*72 + s] = xv.w;
    }
    __syncthreads();
    int wave = tid >> 6, lane = tid & 63, quad = lane >> 4, l15 = lane & 15;
    int wn = (wave & 1)*32, wp = (wave >> 1)*32;
    float4v zero4 = {0.f,0.f,0.f,0.f};
    float4v acc[2][2];
    #pragma unroll
    for (int mi=0;mi<2;mi++)
        #pragma unroll
        for (int ni=0;ni<2;ni++) acc[mi][ni] = zero4;
    #pragma unroll
    for (int k0=0;k0<64;k0+=32){
        short8v af[2], bfr[2];
        #pragma unroll
        for (int mi=0;mi<2;mi++) af[mi] = *(const short8v*)&Bw[(wn + mi*16 + l15)*72 + k0 + quad*8];
        #pragma unroll
        for (int ni=0;ni<2;ni++) bfr[ni] = *(const short8v*)&Xt[(wp + ni*16 + l15)*72 + k0 + quad*8];
        #pragma unroll
        for (int mi=0;mi<2;mi++)
            #pragma unroll
            for (int ni=0;ni<2;ni++)
                acc[mi][ni] = __builtin_amdgcn_mfma_f32_16x16x32_bf16(af[mi], bfr[ni], acc[mi][ni], 0, 0, 0);
    }
    size_t Sbase = ((size_t)bh*NCH + kk)*4096;
    #pragma unroll
    for (int mi=0;mi<2;mi++){
        #pragma unroll
        for (int ni=0;ni<2;ni++){
            int p = wp + ni*16 + l15;
            #pragma unroll
            for (int reg=0;reg<4;reg++){
                int n = wn + mi*16 + quad*4 + reg;
                S[Sbase + n*64 + p] = acc[mi][ni][reg];
            }
        }
    }
}

// ------- combine: 4-way split over the p dimension (grid.z) -------
__global__ __launch_bounds__(256) void k_combine(const float* __restrict__ cum,
                                                 float* __restrict__ S){
    int h = blockIdx.x, b = blockIdx.y, z = blockIdx.z;
    int bh = b*NH + h;
    int tid = threadIdx.x;
    float4 st = make_float4(0.f,0.f,0.f,0.f);
    size_t base0 = ((size_t)bh*NCH)*4096 + (size_t)z*1024 + (size_t)tid*4;
    for (int k=0;k<NCH;k++){
        size_t base = base0 + (size_t)k*4096;
        float dk = __expf(fminf(cum[bh*L_ + k*Q_ + 63], 0.f));
        float4 a = *(const float4*)&S[base];
        *(float4*)&S[base] = st;
        st.x = a.x + dk*st.x;
        st.y = a.y + dk*st.y;
        st.z = a.z + dk*st.z;
        st.w = a.w + dk*st.w;
    }
}

// ------- finalize2: reads precomputed conv output (cvb); Ml aliases Bs -------
__global__ __launch_bounds__(256) void k_finalize2(const unsigned short* __restrict__ cvb,
                                                   const float* __restrict__ dt,
                                                   const float* __restrict__ cum,
                                                   const float* __restrict__ Dp,
                                                   const float* __restrict__ S,
                                                   unsigned short* __restrict__ yB){
    __shared__ unsigned short Ct[64*72];
    __shared__ unsigned short Bs[64*72];   // aliased as Ml after GEMM1
    __shared__ unsigned short Xt[64*72];
    __shared__ unsigned short St[64*72];
    __shared__ float sdt[64], scum[64];
    unsigned short* const Ml = &Bs[0];
    int kk, h, b;
    grp_map(blockIdx.x, kk, h, b);
    int tid = threadIdx.x;
    int bh = b*NH + h;
    int l0 = kk*Q_;
    if (tid < 64){
        int base = bh*L_ + l0;
        sdt[tid] = dt[base + tid];
        scum[tid] = cum[base + tid];
    }
    int rr = tid >> 4, c0 = (tid & 15)*4;
    size_t Sbase = ((size_t)bh*NCH + kk)*4096;
    #pragma unroll
    for (int i=0;i<4;i++){
        int r = rr + i*16;
        size_t rb = ((size_t)(b*L_ + l0 + r))*CD;
        *(ushort4*)&Ct[r*72 + c0] = *(const ushort4*)&cvb[rb + DI + DS + c0];
        *(ushort4*)&Bs[r*72 + c0] = *(const ushort4*)&cvb[rb + DI + c0];
        ushort4 xv = *(const ushort4*)&cvb[rb + h*HD + c0];
        Xt[(c0+0)*72 + r] = xv.x;
        Xt[(c0+1)*72 + r] = xv.y;
        Xt[(c0+2)*72 + r] = xv.z;
        Xt[(c0+3)*72 + r] = xv.w;
        float4 sv = *(const float4*)&S[Sbase + r*64 + c0];
        St[(c0+0)*72 + r] = f2bu(sv.x);
        St[(c0+1)*72 + r] = f2bu(sv.y);
        St[(c0+2)*72 + r] = f2bu(sv.z);
        St[(c0+3)*72 + r] = f2bu(sv.w);
    }
    __syncthreads();
    int wave = tid >> 6, lane = tid & 63, quad = lane >> 4, l15 = lane & 15;
    int wt2 = (wave & 1)*32, wc = (wave >> 1)*32;
    float4v zero4 = {0.f,0.f,0.f,0.f};
    {
        float4v acc[2][2];
        #pragma unroll
        for (int mi=0;mi<2;mi++)
            #pragma unroll
            for (int ni=0;ni<2;ni++) acc[mi][ni] = zero4;
        #pragma unroll
        for (int k0=0;k0<64;k0+=32){
            short8v af[2], bfr[2];
            #pragma unroll
            for (int mi=0;mi<2;mi++) af[mi] = *(const short8v*)&Ct[(wt2 + mi*16 + l15)*72 + k0 + quad*8];
            #pragma unroll
            for (int ni=0;ni<2;ni++) bfr[ni] = *(const short8v*)&Bs[(wc + ni*16 + l15)*72 + k0 + quad*8];
            #pragma unroll
            for (int mi=0;mi<2;mi++)
                #pragma unroll
                for (int ni=0;ni<2;ni++)
                    acc[mi][ni] = __builtin_amdgcn_mfma_f32_16x16x32_bf16(af[mi], bfr[ni], acc[mi][ni], 0, 0, 0);
        }
        __syncthreads();   // all waves done reading Bs before it becomes Ml
        #pragma unroll
        for (int mi=0;mi<2;mi++){
            #pragma unroll
            for (int ni=0;ni<2;ni++){
                int s = wc + ni*16 + l15;
                #pragma unroll
                for (int reg=0;reg<4;reg++){
                    int t = wt2 + mi*16 + quad*4 + reg;
                    float m = (s <= t) ? acc[mi][ni][reg]*sdt[s]*__expf(fminf(scum[t]-scum[s], 0.f)) : 0.f;
                    Ml[t*72 + s] = f2bu(m);
                }
            }
        }
    }
    __syncthreads();
    {
        float4v a1[2][2], a2[2][2];
        #pragma unroll
        for (int mi=0;mi<2;mi++)
            #pragma unroll
            for (int ni=0;ni<2;ni++){ a1[mi][ni] = zero4; a2[mi][ni] = zero4; }
        #pragma unroll
        for (int k0=0;k0<64;k0+=32){
            short8v mf[2], cf[2], xf[2], sf[2];
            #pragma unroll
            for (int mi=0;mi<2;mi++){
                mf[mi] = *(const short8v*)&Ml[(wt2 + mi*16 + l15)*72 + k0 + quad*8];
                cf[mi] = *(const short8v*)&Ct[(wt2 + mi*16 + l15)*72 + k0 + quad*8];
            }
            #pragma unroll
            for (int ni=0;ni<2;ni++){
                xf[ni] = *(const short8v*)&Xt[(wc + ni*16 + l15)*72 + k0 + quad*8];
                sf[ni] = *(const short8v*)&St[(wc + ni*16 + l15)*72 + k0 + quad*8];
            }
            #pragma unroll
            for (int mi=0;mi<2;mi++)
                #pragma unroll
                for (int ni=0;ni<2;ni++){
                    a1[mi][ni] = __builtin_amdgcn_mfma_f32_16x16x32_bf16(mf[mi], xf[ni], a1[mi][ni], 0, 0, 0);
                    a2[mi][ni] = __builtin_amdgcn_mfma_f32_16x16x32_bf16(cf[mi], sf[ni], a2[mi][ni], 0, 0, 0);
                }
        }
        float Dh = Dp[h];
        #pragma unroll
        for (int mi=0;mi<2;mi++){
            #pragma unroll
            for (int ni=0;ni<2;ni++){
                int p = wc + ni*16 + l15;
                #pragma unroll
                for (int reg=0;reg<4;reg++){
                    int t = wt2 + mi*16 + quad*4 + reg;
                    float e = __expf(fminf(scum[t], 0.f));
                    float xval = u2f(Xt[p*72 + t]);
                    yB[(size_t)(b*L_ + l0 + t)*DI + h*HD + p] =
                        f2bu(a1[mi][ni][reg] + e*a2[mi][ni][reg] + Dh*xval);
                }
            }
        }
    }
}

__global__ __launch_bounds__(256) void k_gaterms(const unsigned short* __restrict__ z,
                                                 const float* __restrict__ rw,
                                                 const unsigned short* __restrict__ yB,
                                                 unsigned short* __restrict__ ybf){
    __shared__ float red[4];
    int row = blockIdx.x;
    int tid = threadIdx.x;
    float g[2]; float ss = 0.f;
    #pragma unroll
    for (int r=0;r<2;r++){
        int d = tid + r*256;
        float zv = u2f(z[(size_t)row*DI + d]);
        float yv = u2f(yB[(size_t)row*DI + d]);
        float gv = yv * siluf_(zv);
        g[r] = gv;
        ss += gv*gv;
    }
    float tot = blockSum256(ss, red);
    float rinv = rsqrtf(tot*(1.f/512.f) + EPS_);
    #pragma unroll
    for (int r=0;r<2;r++){
        int d = tid + r*256;
        ybf[(size_t)row*DI + d] = f2bu(g[r]*rinv*rw[d]);
    }
}

__global__ __launch_bounds__(256) void k_ln(const float* __restrict__ h,
                                            const float* __restrict__ lw,
                                            const float* __restrict__ lb,
                                            float* __restrict__ out){
    __shared__ float red[4];
    int row = blockIdx.x;
    int tid = threadIdx.x;
    float v = h[(size_t)row*DM + tid];
    float mu = blockSum256(v, red)*(1.f/256.f);
    float d = v - mu;
    float var = blockSum256(d*d, red)*(1.f/256.f);
    out[(size_t)row*DM + tid] = d*rsqrtf(var + EPS_)*lw[tid] + lb[tid];
}

__global__ __launch_bounds__(256) void k_meanl(const float* __restrict__ ln,
                                               float* __restrict__ hmp,
                                               int b0){
    int g = blockIdx.x, bl = blockIdx.y;
    int tid = threadIdx.x;
    float s = 0.f;
    for (int i=0;i<128;i++){
        int l = g*128 + i;
        s += ln[(size_t)(bl*L_ + l)*DM + tid];
    }
    hmp[((size_t)(b0+bl)*16 + g)*DM + tid] = s*(1.f/2048.f);
}

__global__ __launch_bounds__(256) void k_heads(const float* __restrict__ hmp,
                                               const float* __restrict__ dw,
                                               const float* __restrict__ db,
                                               const float* __restrict__ rw,
                                               const float* __restrict__ rb,
                                               float* __restrict__ out){
    __shared__ float red[4];
    int b = blockIdx.x;
    int tid = threadIdx.x;
    float hv = 0.f;
    #pragma unroll
    for (int g=0; g<16; g++) hv += hmp[((size_t)b*16 + g)*DM + tid];
    float s0 = hv*dw[tid];
    float s1 = hv*rw[tid*3+0];
    float s2 = hv*rw[tid*3+1];
    float s3 = hv*rw[tid*3+2];
    s0 = blockSum256(s0, red);
    s1 = blockSum256(s1, red);
    s2 = blockSum256(s2, red);
    s3 = blockSum256(s3, red);
    if (tid == 0){
        out[b] = s0 + db[0];
        out[16 + b*3 + 0] = s1 + rb[0];
        out[16 + b*3 + 1] = s2 + rb[1];
        out[16 + b*3 + 2] = s3 + rb[2];
    }
}

extern "C" void kernel_launch(void* const* d_in, const int* in_sizes, int n_in,
                              void* d_out, int out_size, void* d_ws, size_t ws_size,
                              hipStream_t stream){
    static const int expSizes[NIN] = {1507328,11776,256,1187840,10240,2560,32,32,32,2048,524288,256,256,256,1,768,3};
    float* out = (float*)d_out;

    if (n_in != NIN){
        k_sentinel<<<1,64,0,stream>>>(out, 9.0e6f);
        return;
    }
    for (int i=0;i<NIN;i++){
        if (in_sizes[i] != expSizes[i]){
            k_sentinel<<<1,64,0,stream>>>(out, (float)(i+1)*1.0e5f);
            return;
        }
    }
    size_t need16 = ((size_t)SLICEOFF + 2048ull*PERROW)*4ull;
    if (ws_size < need16){
        float mb = (float)(ws_size >> 20);
        k_sentinel<<<1,64,0,stream>>>(out, 2.0e7f + mb*131072.f);
        return;
    }

    float* ws = (float*)d_ws;
    int* flags = (int*)d_ws;
    float* stg = ws + STGOFF;
    unsigned short* ipwT = (unsigned short*)(ws + WIPT);
    unsigned short* opwT = (unsigned short*)(ws + WOPT);
    float* hmp = ws + HMPOFF;

    PtrTab pt;
    for (int i=0;i<NIN;i++) pt.p[i] = d_in[i];

    k_detect<<<NIN, 256, 0, stream>>>(pt, flags);
    k_stage<<<dim3(8, NSMALL), 256, 0, stream>>>(pt, flags, stg);
    k_wip<<<dim3(NP, NL), 256, 0, stream>>>(d_in[3], flags+3, ipwT);
    k_wop<<<dim3(DM, NL), 256, 0, stream>>>(d_in[10], flags+10, opwT);

    const float* inp_w = stg + 0;
    const float* inp_b = stg + 11776;
    const float* cw    = stg + 12032;
    const float* cb    = stg + 22272;
    const float* dtb   = stg + 24832;
    const float* alog  = stg + 24864;
    const float* Dp    = stg + 24896;
    const float* rmsw  = stg + 24928;
    const float* lnw   = stg + 26976;
    const float* lnb   = stg + 27232;
    const float* dw    = stg + 27488;
    const float* db    = stg + 27744;
    const float* rw    = stg + 27748;
    const float* rb    = stg + 28516;

    int nsl = 1;
    while (((size_t)SLICEOFF + ((size_t)MROWS/nsl)*PERROW)*4ull > ws_size) nsl <<= 1;
    const size_t R = (size_t)MROWS / nsl;
    const int SB = B_ / nsl;

    float* base = ws + SLICEOFF;
    // Layout (floats-per-row offsets, lifetime-aliased):
    //   hbuf [0,256) f32 | hbf [256,384) bf16 | zb [384,640) bf16
    //   xbb  [640,964) bf16 (raw xBC+dt; dead after dtcum) -- ybB aliases [640,896)
    //   cvb  [964,1284) bf16 (conv+SiLU; dead after finalize2) -- ybf aliases [964,1220)
    //   S    [1284,1796) f32 (also LN scratch) | dt [1796,1804) | cum [1804,1812)
    float* hbuf = base;
    unsigned short* hbf  = (unsigned short*)(base + R*256);
    unsigned short* zb   = (unsigned short*)(base + R*384);
    unsigned short* xbb  = (unsigned short*)(base + R*640);
    unsigned short* ybB  = (unsigned short*)(base + R*640);   // alias: xbb dead after dtcum
    unsigned short* cvb  = (unsigned short*)(base + R*964);
    unsigned short* ybf  = (unsigned short*)(base + R*964);   // alias: cvb dead after finalize2
    float* S   = base + R*1284;
    float* dt  = base + R*1796;
    float* cum = base + R*1804;

    for (int sl=0; sl<nsl; sl++){
        k_inproj<<<(int)(R/32), 256, 0, stream>>>(d_in[0], flags, (size_t)sl*R*46, inp_w, inp_b, hbuf, hbf);
        for (int li=0; li<NL; li++){
            const float* cwl = cw + li*CD*4;
            const float* cbl = cb + li*CD;
            k_mgemm<0><<<dim3(NP/128, R/64), 256, 0, stream>>>(
                hbf, ipwT + (size_t)li*NP*DM, hbuf, zb, xbb, ybf, DM);
            k_conv<<<dim3(10, (int)(R/64)), 256, 0, stream>>>(xbb, cwl, cbl, cvb);
            k_dtcum<<<dim3(NCH,NH,SB), 64, 0, stream>>>(xbb, dtb + li*NH, alog + li*NH, dt, cum);
            k_passS<<<NCH*NH*SB, 256, 0, stream>>>(cvb, dt, cum, S);
            k_combine<<<dim3(NH,SB,4), 256, 0, stream>>>(cum, S);
            k_finalize2<<<NCH*NH*SB, 256, 0, stream>>>(cvb, dt, cum, Dp + li*NH, S, ybB);
            k_gaterms<<<(int)R, 256, 0, stream>>>(zb, rmsw + li*DI, ybB, ybf);
            k_mgemm<1><<<dim3(DM/128, R/64), 256, 0, stream>>>(
                ybf, opwT + (size_t)li*DM*DI, hbuf, zb, xbb, hbf, DI);
        }
        k_ln<<<(int)R, 256, 0, stream>>>(hbuf, lnw, lnb, S);
        k_meanl<<<dim3(16,SB), 256, 0, stream>>>(S, hmp, sl*SB);
    }
    k_heads<<<B_, 256, 0, stream>>>(hmp, dw, db, rw, rb, out);
}

// Round 8
// 1041.247 us; speedup vs baseline: 1.1171x; 1.0251x over previous
//
#include <hip/hip_runtime.h>
#include <hip/hip_bf16.h>
#include <math.h>

typedef __hip_bfloat16 bf16;

#define B_ 16
#define L_ 2048
#define DM 256
#define DI 512
#define NH 8
#define HD 64
#define DS 64
#define CD 640
#define DIP 1160
#define XB 648
#define NP 1280
#define NL 4
#define Q_ 64
#define NCH 32
#define MROWS (B_*L_)
#define EPS_ 1e-5f
#define NIN 17
#define NSMALL 14
#define STGOFF 32
#define WIPT 28552
#define WOPT 683912
#define HMPOFF 946056
#define SLICEOFF 1011592
#define PERROW 2004

__device__ __forceinline__ float u2f(unsigned short u){ return __uint_as_float(((unsigned)u)<<16); }
__device__ __forceinline__ unsigned short f2bu(float f){ bf16 h = __float2bfloat16(f); return *(unsigned short*)&h; }
__device__ __forceinline__ float sigmoidf_(float x){ return 1.f/(1.f+__expf(-x)); }
__device__ __forceinline__ float siluf_(float x){ return x*sigmoidf_(x); }
__device__ __forceinline__ float softplusf_(float x){ return (x>20.f)? x : log1pf(__expf(x)); }

typedef __attribute__((ext_vector_type(8))) short short8v;
typedef __attribute__((ext_vector_type(4))) float float4v;
typedef __attribute__((ext_vector_type(8))) unsigned short ush8;

__device__ const int kN17[NIN] = {1507328,11776,256,1187840,10240,2560,32,32,32,2048,524288,256,256,256,1,768,3};
__device__ const int sIdx[NSMALL] = {1,2,4,5,6,7,8,9,11,12,13,14,15,16};
__device__ const int sNum[NSMALL] = {11776,256,10240,2560,32,32,32,2048,256,256,256,1,768,3};
__device__ const int sOff[NSMALL] = {0,11776,12032,22272,24832,24864,24896,24928,26976,27232,27488,27744,27748,28516};

struct PtrTab { const void* p[NIN]; };

__global__ __launch_bounds__(64) void k_sentinel(float* out, float v){
    int t = threadIdx.x;
    out[t] = (t==0) ? v : 0.f;
}

__global__ __launch_bounds__(256) void k_detect(PtrTab t, int* flags){
    int i = blockIdx.x;
    int n = kN17[i];
    int S = n < 4096 ? n : 4096;
    const unsigned short* u = (const unsigned short*)t.p[i];
    __shared__ int big, ze, zo, so;
    if (threadIdx.x == 0){ big=0; ze=0; zo=0; so=0; }
    __syncthreads();
    int lbig=0, lze=0, lzo=0, lso=0;
    for (int j=threadIdx.x; j<S; j+=256){
        unsigned short v = u[j];
        int e = (v>>7)&0xFF;
        if (e >= 131) lbig = 1;
        int isz = ((v & 0x7FFF) == 0) ? 1 : 0;
        if (j & 1){ lso++; lzo += isz; } else { lze += isz; }
    }
    if (lbig) atomicOr(&big, 1);
    atomicAdd(&ze, lze); atomicAdd(&zo, lzo); atomicAdd(&so, lso);
    __syncthreads();
    if (threadIdx.x == 0){
        int Se = S - so;
        flags[i] = (big || (so > 0 && 4*ze >= 3*Se && 4*zo <= so)) ? 1 : 0;
    }
}

__global__ __launch_bounds__(256) void k_stage(PtrTab t, const int* __restrict__ flags,
                                               float* __restrict__ stg){
    int a = blockIdx.y;
    int idx = sIdx[a];
    int n = sNum[a];
    float* dst = stg + sOff[a];
    const void* p = t.p[idx];
    if (flags[idx]){
        const float* s = (const float*)p;
        for (int j=blockIdx.x*256+threadIdx.x; j<n; j += gridDim.x*256) dst[j] = s[j];
    } else {
        const unsigned short* s = (const unsigned short*)p;
        for (int j=blockIdx.x*256+threadIdx.x; j<n; j += gridDim.x*256) dst[j] = u2f(s[j]);
    }
}

__global__ __launch_bounds__(256) void k_wip(const void* __restrict__ src,
                                             const int* __restrict__ flag,
                                             unsigned short* __restrict__ dst){
    int n = blockIdx.x, l = blockIdx.y, k = threadIdx.x;
    unsigned short b = 0;
    if (n < DIP){
        size_t si = ((size_t)l*DM + k)*DIP + n;
        if (flag[0]) b = f2bu(((const float*)src)[si]);
        else         b = ((const unsigned short*)src)[si];
    }
    dst[((size_t)l*NP + n)*DM + k] = b;
}

__global__ __launch_bounds__(256) void k_wop(const void* __restrict__ src,
                                             const int* __restrict__ flag,
                                             unsigned short* __restrict__ dst){
    int n = blockIdx.x, l = blockIdx.y;
    for (int k = threadIdx.x; k < DI; k += 256){
        size_t si = ((size_t)l*DI + k)*DM + n;
        unsigned short b;
        if (flag[0]) b = f2bu(((const float*)src)[si]);
        else         b = ((const unsigned short*)src)[si];
        dst[((size_t)l*DM + n)*DI + k] = b;
    }
}

__device__ __forceinline__ float blockSum256(float v, float* red){
    #pragma unroll
    for (int off=32; off>0; off>>=1) v += __shfl_down(v, off);
    if ((threadIdx.x & 63) == 0) red[threadIdx.x >> 6] = v;
    __syncthreads();
    float s = red[0] + red[1] + red[2] + red[3];
    __syncthreads();
    return s;
}

// ------- inproj: 32 rows per block; w read once per block, reused 32x -------
__global__ __launch_bounds__(256) void k_inproj(const void* __restrict__ x,
                                                const int* __restrict__ flags,
                                                size_t xoff,
                                                const float* __restrict__ w,
                                                const float* __restrict__ bias,
                                                float* __restrict__ h,
                                                unsigned short* __restrict__ hbf){
    __shared__ float xs[32*46];
    int row0 = blockIdx.x*32;
    int t = threadIdx.x;
    bool f32 = flags[0] != 0;
    for (int j = t; j < 32*46; j += 256){
        size_t gi = xoff + (size_t)row0*46 + j;
        xs[j] = f32 ? ((const float*)x)[gi] : u2f(((const unsigned short*)x)[gi]);
    }
    __syncthreads();
    float bv = bias[t];
    float acc[32];
    #pragma unroll
    for (int r=0;r<32;r++) acc[r] = bv;
    for (int k=0;k<46;k++){
        float wv = w[k*DM + t];
        #pragma unroll
        for (int r=0;r<32;r++) acc[r] += xs[r*46 + k]*wv;
    }
    #pragma unroll
    for (int r=0;r<32;r++){
        size_t o = (size_t)(row0 + r)*DM + t;
        h[o] = acc[r];
        hbf[o] = f2bu(acc[r]);
    }
}

// ------- mgemm: 64x128 tile, reg-staged K-loop (round-3 proven) +
// LDS-transpose epilogue: accumulators round-trip a 17KB LDS buffer so each
// thread stores 8 consecutive cols as one 16B dwordx4 (fully coalesced),
// replacing the 2B-per-lane scattered stores (4 partial-line L2 write
// transactions per 128B) that were the structure-invariant bottleneck.
template<int MODE>
__global__ __launch_bounds__(256, 4) void k_mgemm(const unsigned short* __restrict__ A,
                                                  const unsigned short* __restrict__ Bt,
                                                  float* __restrict__ O1,
                                                  unsigned short* __restrict__ O1b,
                                                  unsigned short* __restrict__ O2b,
                                                  unsigned short* __restrict__ O3,
                                                  int K){
    // LDS pool: staging As(5120B)+Bs(10240B)=15360B; epilogue 32*132*4=16896B (reused)
    __shared__ __align__(16) char ldsraw[16896];
    unsigned short* As = (unsigned short*)ldsraw;            // 64*40 shorts
    unsigned short* Bs = (unsigned short*)(ldsraw + 5120);   // 128*40 shorts
    int tid = threadIdx.x;
    int wave = tid >> 6, lane = tid & 63, quad = lane >> 4, l15 = lane & 15;
    // XCD-aware bijective swizzle (nwg%8==0 for all grids here).
    int p = blockIdx.y * gridDim.x + blockIdx.x;
    int nwg = gridDim.x * gridDim.y;
    int cpx = nwg >> 3;
    int logical = (p & 7) * cpx + (p >> 3);
    int by = logical / gridDim.x;
    int bx = logical - by * gridDim.x;
    int mbase = by*64, nbase = bx*128;
    int wm = (wave & 1)*32, wn = (wave >> 1)*64;
    float4v zero4 = {0.f,0.f,0.f,0.f};
    float4v acc[2][4];
    #pragma unroll
    for (int mi=0;mi<2;mi++)
        #pragma unroll
        for (int ni=0;ni<4;ni++) acc[mi][ni] = zero4;

    int rowA = tid >> 2, koffA = (tid & 3)*8;
    const unsigned short* Ap = A + (size_t)(mbase+rowA)*K + koffA;
    for (int k0 = 0; k0 < K; k0 += 32){
        *(uint4*)&As[rowA*40 + koffA] = *(const uint4*)&Ap[k0];
        #pragma unroll
        for (int i=0;i<2;i++){
            int c = tid + i*256;
            int row = c >> 2, koff = (c & 3)*8;
            *(uint4*)&Bs[row*40 + koff] = *(const uint4*)&Bt[(size_t)(nbase+row)*K + k0 + koff];
        }
        __syncthreads();
        short8v af[2], bfr[4];
        #pragma unroll
        for (int mi=0;mi<2;mi++) af[mi] = *(const short8v*)&As[(wm + mi*16 + l15)*40 + quad*8];
        #pragma unroll
        for (int ni=0;ni<4;ni++) bfr[ni] = *(const short8v*)&Bs[(wn + ni*16 + l15)*40 + quad*8];
        #pragma unroll
        for (int mi=0;mi<2;mi++)
            #pragma unroll
            for (int ni=0;ni<4;ni++)
                acc[mi][ni] = __builtin_amdgcn_mfma_f32_16x16x32_bf16(af[mi], bfr[ni], acc[mi][ni], 0, 0, 0);
        __syncthreads();
    }

    // ---- vectorized epilogue via LDS transpose: two 32-row halves ----
    float* ep = (float*)ldsraw;     // 32 x 132 f32 (staging dead; loop's trailing barrier passed)
    int erow = tid >> 4;            // 0..15
    int ecc  = (tid & 15) * 8;      // 0..120
    #pragma unroll
    for (int half = 0; half < 2; ++half){
        if ((wave & 1) == half){
            #pragma unroll
            for (int mi=0;mi<2;mi++){
                #pragma unroll
                for (int ni=0;ni<4;ni++){
                    int col = wn + ni*16 + l15;
                    #pragma unroll
                    for (int reg=0;reg<4;reg++){
                        int r = mi*16 + quad*4 + reg;    // 0..31 within half
                        ep[r*132 + col] = acc[mi][ni][reg];
                    }
                }
            }
        }
        __syncthreads();
        #pragma unroll
        for (int ps=0; ps<2; ps++){
            int r = ps*16 + erow;
            int growg = mbase + half*32 + r;
            int colg = nbase + ecc;
            float4 v0 = *(const float4*)&ep[r*132 + ecc + 0];
            float4 v1 = *(const float4*)&ep[r*132 + ecc + 4];
            if (MODE == 0){
                ush8 ob;
                ob[0]=f2bu(v0.x); ob[1]=f2bu(v0.y); ob[2]=f2bu(v0.z); ob[3]=f2bu(v0.w);
                ob[4]=f2bu(v1.x); ob[5]=f2bu(v1.y); ob[6]=f2bu(v1.z); ob[7]=f2bu(v1.w);
                if (colg + 8 <= DI){
                    *(ush8*)&O1b[(size_t)growg*DI + colg] = ob;
                } else if (colg >= DI && colg + 8 <= DIP){
                    *(ush8*)&O2b[(size_t)growg*XB + (colg - DI)] = ob;
                }
                // cols >= DIP (1160..1279) are dead padding: skip
            } else {
                size_t ob1 = (size_t)growg*DM + colg;
                float4 h0 = *(const float4*)&O1[ob1];
                float4 h1 = *(const float4*)&O1[ob1+4];
                h0.x+=v0.x; h0.y+=v0.y; h0.z+=v0.z; h0.w+=v0.w;
                h1.x+=v1.x; h1.y+=v1.y; h1.z+=v1.z; h1.w+=v1.w;
                *(float4*)&O1[ob1] = h0;
                *(float4*)&O1[ob1+4] = h1;
                ush8 ob;
                ob[0]=f2bu(h0.x); ob[1]=f2bu(h0.y); ob[2]=f2bu(h0.z); ob[3]=f2bu(h0.w);
                ob[4]=f2bu(h1.x); ob[5]=f2bu(h1.y); ob[6]=f2bu(h1.z); ob[7]=f2bu(h1.w);
                *(ush8*)&O3[ob1] = ob;
            }
        }
        __syncthreads();
    }
}

// ------- one-pass depthwise conv + SiLU over all CD channels -> cvb -------
__global__ __launch_bounds__(256) void k_conv(const unsigned short* __restrict__ xbb,
                                              const float* __restrict__ cw,
                                              const float* __restrict__ cb,
                                              unsigned short* __restrict__ cvb){
    int tid = threadIdx.x;
    int c0 = (blockIdx.x*16 + (tid & 15))*4;
    int r0 = blockIdx.y*64 + (tid >> 4);
    float wA[4], wB[4], wC[4], wD[4];
    {
        float4 t0 = *(const float4*)&cw[(size_t)(c0+0)*4];
        float4 t1 = *(const float4*)&cw[(size_t)(c0+1)*4];
        float4 t2 = *(const float4*)&cw[(size_t)(c0+2)*4];
        float4 t3 = *(const float4*)&cw[(size_t)(c0+3)*4];
        wA[0]=t0.x; wA[1]=t0.y; wA[2]=t0.z; wA[3]=t0.w;
        wB[0]=t1.x; wB[1]=t1.y; wB[2]=t1.z; wB[3]=t1.w;
        wC[0]=t2.x; wC[1]=t2.y; wC[2]=t2.z; wC[3]=t2.w;
        wD[0]=t3.x; wD[1]=t3.y; wD[2]=t3.z; wD[3]=t3.w;
    }
    float4 bb = *(const float4*)&cb[c0];
    #pragma unroll
    for (int i=0;i<4;i++){
        int r = r0 + i*16;
        int l = r & (L_-1);
        float a0=bb.x, a1=bb.y, a2=bb.z, a3=bb.w;
        #pragma unroll
        for (int j=0;j<4;j++){
            if (l-3+j >= 0){
                ushort4 uv = *(const ushort4*)&xbb[(size_t)(r-3+j)*XB + c0];
                a0 += u2f(uv.x)*wA[j];
                a1 += u2f(uv.y)*wB[j];
                a2 += u2f(uv.z)*wC[j];
                a3 += u2f(uv.w)*wD[j];
            }
        }
        ushort4 ov;
        ov.x = f2bu(siluf_(a0));
        ov.y = f2bu(siluf_(a1));
        ov.z = f2bu(siluf_(a2));
        ov.w = f2bu(siluf_(a3));
        *(ushort4*)&cvb[(size_t)r*CD + c0] = ov;
    }
}

__global__ __launch_bounds__(64) void k_dtcum(const unsigned short* __restrict__ xb,
                                              const float* __restrict__ dtb,
                                              const float* __restrict__ alog,
                                              float* __restrict__ dto,
                                              float* __restrict__ cumo){
    int kk = blockIdx.x, h = blockIdx.y, b = blockIdx.z;
    int t = threadIdx.x;
    int l = kk*Q_ + t;
    float raw = u2f(xb[(size_t)(b*L_ + l)*XB + CD + h]);
    float dtv = softplusf_(raw + dtb[h]);
    float A = -__expf(alog[h]);
    float s = dtv * A;
    #pragma unroll
    for (int off=1; off<64; off<<=1){
        float u = __shfl_up(s, off);
        if (t >= off) s += u;
    }
    int base = (b*NH + h)*L_ + l;
    dto[base] = dtv;
    cumo[base] = s;
}

// Group-local remap: the 8 h-blocks of one (kk,b) group all get p%8==g%8,
// i.e. the same XCD -> the shared B/C tile is fetched into that L2 once.
__device__ __forceinline__ void grp_map(int p, int &kk, int &h, int &b){
    int c = p & 7, i = p >> 3;
    h = i & 7;
    int g = (i & ~7) | c;
    kk = g & (NCH-1);
    b = g >> 5;
}

// ------- passS: reads precomputed conv output (cvb) -------
__global__ __launch_bounds__(256) void k_passS(const unsigned short* __restrict__ cvb,
                                               const float* __restrict__ dt,
                                               const float* __restrict__ cum,
                                               float* __restrict__ S){
    __shared__ unsigned short Bw[64*72];
    __shared__ unsigned short Xt[64*72];
    __shared__ float sw[64];
    int kk, h, b;
    grp_map(blockIdx.x, kk, h, b);
    int tid = threadIdx.x;
    int bh = b*NH + h;
    int l0 = kk*Q_;
    if (tid < 64){
        int base = bh*L_ + l0;
        float c = cum[base + tid];
        float c63 = cum[base + 63];
        sw[tid] = dt[base + tid]*__expf(fminf(c63 - c, 0.f));
    }
    __syncthreads();
    int srow = tid >> 4, c0 = (tid & 15)*4;
    #pragma unroll
    for (int i=0;i<4;i++){
        int s = srow + i*16;
        size_t rb = ((size_t)(b*L_ + l0 + s))*CD;
        ushort4 bv = *(const ushort4*)&cvb[rb + DI + c0];
        ushort4 xv = *(const ushort4*)&cvb[rb + h*HD + c0];
        float w = sw[s];
        Bw[(c0+0)*72 + s] = f2bu(w*u2f(bv.x));
        Bw[(c0+1)*72 + s] = f2bu(w*u2f(bv.y));
        Bw[(c0+2)*72 + s] = f2bu(w*u2f(bv.z));
        Bw[(c0+3)*72 + s] = f2bu(w*u2f(bv.w));
        Xt[(c0+0)*72 + s] = xv.x;
        Xt[(c0+1)*72 + s] = xv.y;
        Xt[(c0+2)*72 + s] = xv.z;
        Xt[(c0+3)*72 + s] = xv.w;
    }
    __syncthreads();
    int wave = tid >> 6, lane = tid & 63, quad = lane >> 4, l15 = lane & 15;
    int wn = (wave & 1)*32, wp = (wave >> 1)*32;
    float4v zero4 = {0.f,0.f,0.f,0.f};
    float4v acc[2][2];
    #pragma unroll
    for (int mi=0;mi<2;mi++)
        #pragma unroll
        for (int ni=0;ni<2;ni++) acc[mi][ni] = zero4;
    #pragma unroll
    for (int k0=0;k0<64;k0+=32){
        short8v af[2], bfr[2];
        #pragma unroll
        for (int mi=0;mi<2;mi++) af[mi] = *(const short8v*)&Bw[(wn + mi*16 + l15)*72 + k0 + quad*8];
        #pragma unroll
        for (int ni=0;ni<2;ni++) bfr[ni] = *(const short8v*)&Xt[(wp + ni*16 + l15)*72 + k0 + quad*8];
        #pragma unroll
        for (int mi=0;mi<2;mi++)
            #pragma unroll
            for (int ni=0;ni<2;ni++)
                acc[mi][ni] = __builtin_amdgcn_mfma_f32_16x16x32_bf16(af[mi], bfr[ni], acc[mi][ni], 0, 0, 0);
    }
    size_t Sbase = ((size_t)bh*NCH + kk)*4096;
    #pragma unroll
    for (int mi=0;mi<2;mi++){
        #pragma unroll
        for (int ni=0;ni<2;ni++){
            int p = wp + ni*16 + l15;
            #pragma unroll
            for (int reg=0;reg<4;reg++){
                int n = wn + mi*16 + quad*4 + reg;
                S[Sbase + n*64 + p] = acc[mi][ni][reg];
            }
        }
    }
}

// ------- combine: 4-way split over the p dimension (grid.z) -------
__global__ __launch_bounds__(256) void k_combine(const float* __restrict__ cum,
                                                 float* __restrict__ S){
    int h = blockIdx.x, b = blockIdx.y, z = blockIdx.z;
    int bh = b*NH + h;
    int tid = threadIdx.x;
    float4 st = make_float4(0.f,0.f,0.f,0.f);
    size_t base0 = ((size_t)bh*NCH)*4096 + (size_t)z*1024 + (size_t)tid*4;
    for (int k=0;k<NCH;k++){
        size_t base = base0 + (size_t)k*4096;
        float dk = __expf(fminf(cum[bh*L_ + k*Q_ + 63], 0.f));
        float4 a = *(const float4*)&S[base];
        *(float4*)&S[base] = st;
        st.x = a.x + dk*st.x;
        st.y = a.y + dk*st.y;
        st.z = a.z + dk*st.z;
        st.w = a.w + dk*st.w;
    }
}

// ------- finalize2: reads precomputed conv output (cvb); Ml aliases Bs -------
__global__ __launch_bounds__(256) void k_finalize2(const unsigned short* __restrict__ cvb,
                                                   const float* __restrict__ dt,
                                                   const float* __restrict__ cum,
                                                   const float* __restrict__ Dp,
                                                   const float* __restrict__ S,
                                                   unsigned short* __restrict__ yB){
    __shared__ unsigned short Ct[64*72];
    __shared__ unsigned short Bs[64*72];   // aliased as Ml after GEMM1
    __shared__ unsigned short Xt[64*72];
    __shared__ unsigned short St[64*72];
    __shared__ float sdt[64], scum[64];
    unsigned short* const Ml = &Bs[0];
    int kk, h, b;
    grp_map(blockIdx.x, kk, h, b);
    int tid = threadIdx.x;
    int bh = b*NH + h;
    int l0 = kk*Q_;
    if (tid < 64){
        int base = bh*L_ + l0;
        sdt[tid] = dt[base + tid];
        scum[tid] = cum[base + tid];
    }
    int rr = tid >> 4, c0 = (tid & 15)*4;
    size_t Sbase = ((size_t)bh*NCH + kk)*4096;
    #pragma unroll
    for (int i=0;i<4;i++){
        int r = rr + i*16;
        size_t rb = ((size_t)(b*L_ + l0 + r))*CD;
        *(ushort4*)&Ct[r*72 + c0] = *(const ushort4*)&cvb[rb + DI + DS + c0];
        *(ushort4*)&Bs[r*72 + c0] = *(const ushort4*)&cvb[rb + DI + c0];
        ushort4 xv = *(const ushort4*)&cvb[rb + h*HD + c0];
        Xt[(c0+0)*72 + r] = xv.x;
        Xt[(c0+1)*72 + r] = xv.y;
        Xt[(c0+2)*72 + r] = xv.z;
        Xt[(c0+3)*72 + r] = xv.w;
        float4 sv = *(const float4*)&S[Sbase + r*64 + c0];
        St[(c0+0)*72 + r] = f2bu(sv.x);
        St[(c0+1)*72 + r] = f2bu(sv.y);
        St[(c0+2)*72 + r] = f2bu(sv.z);
        St[(c0+3)*72 + r] = f2bu(sv.w);
    }
    __syncthreads();
    int wave = tid >> 6, lane = tid & 63, quad = lane >> 4, l15 = lane & 15;
    int wt2 = (wave & 1)*32, wc = (wave >> 1)*32;
    float4v zero4 = {0.f,0.f,0.f,0.f};
    {
        float4v acc[2][2];
        #pragma unroll
        for (int mi=0;mi<2;mi++)
            #pragma unroll
            for (int ni=0;ni<2;ni++) acc[mi][ni] = zero4;
        #pragma unroll
        for (int k0=0;k0<64;k0+=32){
            short8v af[2], bfr[2];
            #pragma unroll
            for (int mi=0;mi<2;mi++) af[mi] = *(const short8v*)&Ct[(wt2 + mi*16 + l15)*72 + k0 + quad*8];
            #pragma unroll
            for (int ni=0;ni<2;ni++) bfr[ni] = *(const short8v*)&Bs[(wc + ni*16 + l15)*72 + k0 + quad*8];
            #pragma unroll
            for (int mi=0;mi<2;mi++)
                #pragma unroll
                for (int ni=0;ni<2;ni++)
                    acc[mi][ni] = __builtin_amdgcn_mfma_f32_16x16x32_bf16(af[mi], bfr[ni], acc[mi][ni], 0, 0, 0);
        }
        __syncthreads();   // all waves done reading Bs before it becomes Ml
        #pragma unroll
        for (int mi=0;mi<2;mi++){
            #pragma unroll
            for (int ni=0;ni<2;ni++){
                int s = wc + ni*16 + l15;
                #pragma unroll
                for (int reg=0;reg<4;reg++){
                    int t = wt2 + mi*16 + quad*4 + reg;
                    float m = (s <= t) ? acc[mi][ni][reg]*sdt[s]*__expf(fminf(scum[t]-scum[s], 0.f)) : 0.f;
                    Ml[t*72 + s] = f2bu(m);
                }
            }
        }
    }
    __syncthreads();
    {
        float4v a1[2][2], a2[2][2];
        #pragma unroll
        for (int mi=0;mi<2;mi++)
            #pragma unroll
            for (int ni=0;ni<2;ni++){ a1[mi][ni] = zero4; a2[mi][ni] = zero4; }
        #pragma unroll
        for (int k0=0;k0<64;k0+=32){
            short8v mf[2], cf[2], xf[2], sf[2];
            #pragma unroll
            for (int mi=0;mi<2;mi++){
                mf[mi] = *(const short8v*)&Ml[(wt2 + mi*16 + l15)*72 + k0 + quad*8];
                cf[mi] = *(const short8v*)&Ct[(wt2 + mi*16 + l15)*72 + k0 + quad*8];
            }
            #pragma unroll
            for (int ni=0;ni<2;ni++){
                xf[ni] = *(const short8v*)&Xt[(wc + ni*16 + l15)*72 + k0 + quad*8];
                sf[ni] = *(const short8v*)&St[(wc + ni*16 + l15)*72 + k0 + quad*8];
            }
            #pragma unroll
            for (int mi=0;mi<2;mi++)
                #pragma unroll
                for (int ni=0;ni<2;ni++){
                    a1[mi][ni] = __builtin_amdgcn_mfma_f32_16x16x32_bf16(mf[mi], xf[ni], a1[mi][ni], 0, 0, 0);
                    a2[mi][ni] = __builtin_amdgcn_mfma_f32_16x16x32_bf16(cf[mi], sf[ni], a2[mi][ni], 0, 0, 0);
                }
        }
        float Dh = Dp[h];
        #pragma unroll
        for (int mi=0;mi<2;mi++){
            #pragma unroll
            for (int ni=0;ni<2;ni++){
                int p = wc + ni*16 + l15;
                #pragma unroll
                for (int reg=0;reg<4;reg++){
                    int t = wt2 + mi*16 + quad*4 + reg;
                    float e = __expf(fminf(scum[t], 0.f));
                    float xval = u2f(Xt[p*72 + t]);
                    yB[(size_t)(b*L_ + l0 + t)*DI + h*HD + p] =
                        f2bu(a1[mi][ni][reg] + e*a2[mi][ni][reg] + Dh*xval);
                }
            }
        }
    }
}

__global__ __launch_bounds__(256) void k_gaterms(const unsigned short* __restrict__ z,
                                                 const float* __restrict__ rw,
                                                 const unsigned short* __restrict__ yB,
                                                 unsigned short* __restrict__ ybf){
    __shared__ float red[4];
    int row = blockIdx.x;
    int tid = threadIdx.x;
    float g[2]; float ss = 0.f;
    #pragma unroll
    for (int r=0;r<2;r++){
        int d = tid + r*256;
        float zv = u2f(z[(size_t)row*DI + d]);
        float yv = u2f(yB[(size_t)row*DI + d]);
        float gv = yv * siluf_(zv);
        g[r] = gv;
        ss += gv*gv;
    }
    float tot = blockSum256(ss, red);
    float rinv = rsqrtf(tot*(1.f/512.f) + EPS_);
    #pragma unroll
    for (int r=0;r<2;r++){
        int d = tid + r*256;
        ybf[(size_t)row*DI + d] = f2bu(g[r]*rinv*rw[d]);
    }
}

__global__ __launch_bounds__(256) void k_ln(const float* __restrict__ h,
                                            const float* __restrict__ lw,
                                            const float* __restrict__ lb,
                                            float* __restrict__ out){
    __shared__ float red[4];
    int row = blockIdx.x;
    int tid = threadIdx.x;
    float v = h[(size_t)row*DM + tid];
    float mu = blockSum256(v, red)*(1.f/256.f);
    float d = v - mu;
    float var = blockSum256(d*d, red)*(1.f/256.f);
    out[(size_t)row*DM + tid] = d*rsqrtf(var + EPS_)*lw[tid] + lb[tid];
}

__global__ __launch_bounds__(256) void k_meanl(const float* __restrict__ ln,
                                               float* __restrict__ hmp,
                                               int b0){
    int g = blockIdx.x, bl = blockIdx.y;
    int tid = threadIdx.x;
    float s = 0.f;
    for (int i=0;i<128;i++){
        int l = g*128 + i;
        s += ln[(size_t)(bl*L_ + l)*DM + tid];
    }
    hmp[((size_t)(b0+bl)*16 + g)*DM + tid] = s*(1.f/2048.f);
}

__global__ __launch_bounds__(256) void k_heads(const float* __restrict__ hmp,
                                               const float* __restrict__ dw,
                                               const float* __restrict__ db,
                                               const float* __restrict__ rw,
                                               const float* __restrict__ rb,
                                               float* __restrict__ out){
    __shared__ float red[4];
    int b = blockIdx.x;
    int tid = threadIdx.x;
    float hv = 0.f;
    #pragma unroll
    for (int g=0; g<16; g++) hv += hmp[((size_t)b*16 + g)*DM + tid];
    float s0 = hv*dw[tid];
    float s1 = hv*rw[tid*3+0];
    float s2 = hv*rw[tid*3+1];
    float s3 = hv*rw[tid*3+2];
    s0 = blockSum256(s0, red);
    s1 = blockSum256(s1, red);
    s2 = blockSum256(s2, red);
    s3 = blockSum256(s3, red);
    if (tid == 0){
        out[b] = s0 + db[0];
        out[16 + b*3 + 0] = s1 + rb[0];
        out[16 + b*3 + 1] = s2 + rb[1];
        out[16 + b*3 + 2] = s3 + rb[2];
    }
}

extern "C" void kernel_launch(void* const* d_in, const int* in_sizes, int n_in,
                              void* d_out, int out_size, void* d_ws, size_t ws_size,
                              hipStream_t stream){
    static const int expSizes[NIN] = {1507328,11776,256,1187840,10240,2560,32,32,32,2048,524288,256,256,256,1,768,3};
    float* out = (float*)d_out;

    if (n_in != NIN){
        k_sentinel<<<1,64,0,stream>>>(out, 9.0e6f);
        return;
    }
    for (int i=0;i<NIN;i++){
        if (in_sizes[i] != expSizes[i]){
            k_sentinel<<<1,64,0,stream>>>(out, (float)(i+1)*1.0e5f);
            return;
        }
    }
    size_t need16 = ((size_t)SLICEOFF + 2048ull*PERROW)*4ull;
    if (ws_size < need16){
        float mb = (float)(ws_size >> 20);
        k_sentinel<<<1,64,0,stream>>>(out, 2.0e7f + mb*131072.f);
        return;
    }

    float* ws = (float*)d_ws;
    int* flags = (int*)d_ws;
    float* stg = ws + STGOFF;
    unsigned short* ipwT = (unsigned short*)(ws + WIPT);
    unsigned short* opwT = (unsigned short*)(ws + WOPT);
    float* hmp = ws + HMPOFF;

    PtrTab pt;
    for (int i=0;i<NIN;i++) pt.p[i] = d_in[i];

    k_detect<<<NIN, 256, 0, stream>>>(pt, flags);
    k_stage<<<dim3(8, NSMALL), 256, 0, stream>>>(pt, flags, stg);
    k_wip<<<dim3(NP, NL), 256, 0, stream>>>(d_in[3], flags+3, ipwT);
    k_wop<<<dim3(DM, NL), 256, 0, stream>>>(d_in[10], flags+10, opwT);

    const float* inp_w = stg + 0;
    const float* inp_b = stg + 11776;
    const float* cw    = stg + 12032;
    const float* cb    = stg + 22272;
    const float* dtb   = stg + 24832;
    const float* alog  = stg + 24864;
    const float* Dp    = stg + 24896;
    const float* rmsw  = stg + 24928;
    const float* lnw   = stg + 26976;
    const float* lnb   = stg + 27232;
    const float* dw    = stg + 27488;
    const float* db    = stg + 27744;
    const float* rw    = stg + 27748;
    const float* rb    = stg + 28516;

    int nsl = 1;
    while (((size_t)SLICEOFF + ((size_t)MROWS/nsl)*PERROW)*4ull > ws_size) nsl <<= 1;
    const size_t R = (size_t)MROWS / nsl;
    const int SB = B_ / nsl;

    float* base = ws + SLICEOFF;
    // Layout (floats-per-row offsets, lifetime-aliased):
    //   hbuf [0,256) f32 | hbf [256,384) bf16 | zb [384,640) bf16
    //   xbb  [640,964) bf16 (raw xBC+dt; dead after dtcum) -- ybB aliases [640,896)
    //   cvb  [964,1284) bf16 (conv+SiLU; dead after finalize2) -- ybf aliases [964,1220)
    //   S    [1284,1796) f32 (also LN scratch) | dt [1796,1804) | cum [1804,1812)
    float* hbuf = base;
    unsigned short* hbf  = (unsigned short*)(base + R*256);
    unsigned short* zb   = (unsigned short*)(base + R*384);
    unsigned short* xbb  = (unsigned short*)(base + R*640);
    unsigned short* ybB  = (unsigned short*)(base + R*640);   // alias: xbb dead after dtcum
    unsigned short* cvb  = (unsigned short*)(base + R*964);
    unsigned short* ybf  = (unsigned short*)(base + R*964);   // alias: cvb dead after finalize2
    float* S   = base + R*1284;
    float* dt  = base + R*1796;
    float* cum = base + R*1804;

    for (int sl=0; sl<nsl; sl++){
        k_inproj<<<(int)(R/32), 256, 0, stream>>>(d_in[0], flags, (size_t)sl*R*46, inp_w, inp_b, hbuf, hbf);
        for (int li=0; li<NL; li++){
            const float* cwl = cw + li*CD*4;
            const float* cbl = cb + li*CD;
            k_mgemm<0><<<dim3(NP/128, R/64), 256, 0, stream>>>(
                hbf, ipwT + (size_t)li*NP*DM, hbuf, zb, xbb, ybf, DM);
            k_conv<<<dim3(10, (int)(R/64)), 256, 0, stream>>>(xbb, cwl, cbl, cvb);
            k_dtcum<<<dim3(NCH,NH,SB), 64, 0, stream>>>(xbb, dtb + li*NH, alog + li*NH, dt, cum);
            k_passS<<<NCH*NH*SB, 256, 0, stream>>>(cvb, dt, cum, S);
            k_combine<<<dim3(NH,SB,4), 256, 0, stream>>>(cum, S);
            k_finalize2<<<NCH*NH*SB, 256, 0, stream>>>(cvb, dt, cum, Dp + li*NH, S, ybB);
            k_gaterms<<<(int)R, 256, 0, stream>>>(zb, rmsw + li*DI, ybB, ybf);
            k_mgemm<1><<<dim3(DM/128, R/64), 256, 0, stream>>>(
                ybf, opwT + (size_t)li*DM*DI, hbuf, zb, xbb, hbf, DI);
        }
        k_ln<<<(int)R, 256, 0, stream>>>(hbuf, lnw, lnb, S);
        k_meanl<<<dim3(16,SB), 256, 0, stream>>>(S, hmp, sl*SB);
    }
    k_heads<<<B_, 256, 0, stream>>>(hmp, dw, db, rw, rb, out);
}

// Round 9
// 998.598 us; speedup vs baseline: 1.1648x; 1.0427x over previous
//
#include <hip/hip_runtime.h>
#include <hip/hip_bf16.h>
#include <math.h>

typedef __hip_bfloat16 bf16;

#define B_ 16
#define L_ 2048
#define DM 256
#define DI 512
#define NH 8
#define HD 64
#define DS 64
#define CD 640
#define DIP 1160
#define XB 648
#define NP 1280
#define NL 4
#define Q_ 64
#define NCH 32
#define MROWS (B_*L_)
#define EPS_ 1e-5f
#define NIN 17
#define NSMALL 14
#define STGOFF 32
#define WIPT 28552
#define WOPT 683912
#define HMPOFF 946056
#define SLICEOFF 1011592
#define PERROW 2004

__device__ __forceinline__ float u2f(unsigned short u){ return __uint_as_float(((unsigned)u)<<16); }
__device__ __forceinline__ unsigned short f2bu(float f){ bf16 h = __float2bfloat16(f); return *(unsigned short*)&h; }
__device__ __forceinline__ float sigmoidf_(float x){ return 1.f/(1.f+__expf(-x)); }
__device__ __forceinline__ float siluf_(float x){ return x*sigmoidf_(x); }
__device__ __forceinline__ float softplusf_(float x){ return (x>20.f)? x : log1pf(__expf(x)); }

typedef __attribute__((ext_vector_type(8))) short short8v;
typedef __attribute__((ext_vector_type(4))) float float4v;
typedef __attribute__((ext_vector_type(8))) unsigned short ush8;

__device__ const int kN17[NIN] = {1507328,11776,256,1187840,10240,2560,32,32,32,2048,524288,256,256,256,1,768,3};
__device__ const int sIdx[NSMALL] = {1,2,4,5,6,7,8,9,11,12,13,14,15,16};
__device__ const int sNum[NSMALL] = {11776,256,10240,2560,32,32,32,2048,256,256,256,1,768,3};
__device__ const int sOff[NSMALL] = {0,11776,12032,22272,24832,24864,24896,24928,26976,27232,27488,27744,27748,28516};

struct PtrTab { const void* p[NIN]; };

__global__ __launch_bounds__(64) void k_sentinel(float* out, float v){
    int t = threadIdx.x;
    out[t] = (t==0) ? v : 0.f;
}

__global__ __launch_bounds__(256) void k_detect(PtrTab t, int* flags){
    int i = blockIdx.x;
    int n = kN17[i];
    int S = n < 4096 ? n : 4096;
    const unsigned short* u = (const unsigned short*)t.p[i];
    __shared__ int big, ze, zo, so;
    if (threadIdx.x == 0){ big=0; ze=0; zo=0; so=0; }
    __syncthreads();
    int lbig=0, lze=0, lzo=0, lso=0;
    for (int j=threadIdx.x; j<S; j+=256){
        unsigned short v = u[j];
        int e = (v>>7)&0xFF;
        if (e >= 131) lbig = 1;
        int isz = ((v & 0x7FFF) == 0) ? 1 : 0;
        if (j & 1){ lso++; lzo += isz; } else { lze += isz; }
    }
    if (lbig) atomicOr(&big, 1);
    atomicAdd(&ze, lze); atomicAdd(&zo, lzo); atomicAdd(&so, lso);
    __syncthreads();
    if (threadIdx.x == 0){
        int Se = S - so;
        flags[i] = (big || (so > 0 && 4*ze >= 3*Se && 4*zo <= so)) ? 1 : 0;
    }
}

__global__ __launch_bounds__(256) void k_stage(PtrTab t, const int* __restrict__ flags,
                                               float* __restrict__ stg){
    int a = blockIdx.y;
    int idx = sIdx[a];
    int n = sNum[a];
    float* dst = stg + sOff[a];
    const void* p = t.p[idx];
    if (flags[idx]){
        const float* s = (const float*)p;
        for (int j=blockIdx.x*256+threadIdx.x; j<n; j += gridDim.x*256) dst[j] = s[j];
    } else {
        const unsigned short* s = (const unsigned short*)p;
        for (int j=blockIdx.x*256+threadIdx.x; j<n; j += gridDim.x*256) dst[j] = u2f(s[j]);
    }
}

__global__ __launch_bounds__(256) void k_wip(const void* __restrict__ src,
                                             const int* __restrict__ flag,
                                             unsigned short* __restrict__ dst){
    int n = blockIdx.x, l = blockIdx.y, k = threadIdx.x;
    unsigned short b = 0;
    if (n < DIP){
        size_t si = ((size_t)l*DM + k)*DIP + n;
        if (flag[0]) b = f2bu(((const float*)src)[si]);
        else         b = ((const unsigned short*)src)[si];
    }
    dst[((size_t)l*NP + n)*DM + k] = b;
}

__global__ __launch_bounds__(256) void k_wop(const void* __restrict__ src,
                                             const int* __restrict__ flag,
                                             unsigned short* __restrict__ dst){
    int n = blockIdx.x, l = blockIdx.y;
    for (int k = threadIdx.x; k < DI; k += 256){
        size_t si = ((size_t)l*DI + k)*DM + n;
        unsigned short b;
        if (flag[0]) b = f2bu(((const float*)src)[si]);
        else         b = ((const unsigned short*)src)[si];
        dst[((size_t)l*DM + n)*DI + k] = b;
    }
}

__global__ __launch_bounds__(256) void k_zerohmp(float* __restrict__ hmp){
    hmp[(size_t)blockIdx.x*256 + threadIdx.x] = 0.f;
}

__device__ __forceinline__ float blockSum256(float v, float* red){
    #pragma unroll
    for (int off=32; off>0; off>>=1) v += __shfl_down(v, off);
    if ((threadIdx.x & 63) == 0) red[threadIdx.x >> 6] = v;
    __syncthreads();
    float s = red[0] + red[1] + red[2] + red[3];
    __syncthreads();
    return s;
}

// ------- inproj: 32 rows per block; w read once per block, reused 32x -------
__global__ __launch_bounds__(256) void k_inproj(const void* __restrict__ x,
                                                const int* __restrict__ flags,
                                                size_t xoff,
                                                const float* __restrict__ w,
                                                const float* __restrict__ bias,
                                                float* __restrict__ h,
                                                unsigned short* __restrict__ hbf){
    __shared__ float xs[32*46];
    int row0 = blockIdx.x*32;
    int t = threadIdx.x;
    bool f32 = flags[0] != 0;
    for (int j = t; j < 32*46; j += 256){
        size_t gi = xoff + (size_t)row0*46 + j;
        xs[j] = f32 ? ((const float*)x)[gi] : u2f(((const unsigned short*)x)[gi]);
    }
    __syncthreads();
    float bv = bias[t];
    float acc[32];
    #pragma unroll
    for (int r=0;r<32;r++) acc[r] = bv;
    for (int k=0;k<46;k++){
        float wv = w[k*DM + t];
        #pragma unroll
        for (int r=0;r<32;r++) acc[r] += xs[r*46 + k]*wv;
    }
    #pragma unroll
    for (int r=0;r<32;r++){
        size_t o = (size_t)(row0 + r)*DM + t;
        h[o] = acc[r];
        hbf[o] = f2bu(acc[r]);
    }
}

// ------- mgemm: 64x128 tile, reg-staged K-loop + LDS-transpose epilogue
// (coalesced 16B dwordx4 stores). ep stride 140 floats for bank spread.
template<int MODE>
__global__ __launch_bounds__(256, 4) void k_mgemm(const unsigned short* __restrict__ A,
                                                  const unsigned short* __restrict__ Bt,
                                                  float* __restrict__ O1,
                                                  unsigned short* __restrict__ O1b,
                                                  unsigned short* __restrict__ O2b,
                                                  unsigned short* __restrict__ O3,
                                                  int K){
    // LDS pool: staging As(5120B)+Bs(10240B)=15360B; epilogue 32*140*4=17920B (reused)
    __shared__ __align__(16) char ldsraw[17920];
    unsigned short* As = (unsigned short*)ldsraw;            // 64*40 shorts
    unsigned short* Bs = (unsigned short*)(ldsraw + 5120);   // 128*40 shorts
    int tid = threadIdx.x;
    int wave = tid >> 6, lane = tid & 63, quad = lane >> 4, l15 = lane & 15;
    // XCD-aware bijective swizzle (nwg%8==0 for all grids here).
    int p = blockIdx.y * gridDim.x + blockIdx.x;
    int nwg = gridDim.x * gridDim.y;
    int cpx = nwg >> 3;
    int logical = (p & 7) * cpx + (p >> 3);
    int by = logical / gridDim.x;
    int bx = logical - by * gridDim.x;
    int mbase = by*64, nbase = bx*128;
    int wm = (wave & 1)*32, wn = (wave >> 1)*64;
    float4v zero4 = {0.f,0.f,0.f,0.f};
    float4v acc[2][4];
    #pragma unroll
    for (int mi=0;mi<2;mi++)
        #pragma unroll
        for (int ni=0;ni<4;ni++) acc[mi][ni] = zero4;

    int rowA = tid >> 2, koffA = (tid & 3)*8;
    const unsigned short* Ap = A + (size_t)(mbase+rowA)*K + koffA;
    for (int k0 = 0; k0 < K; k0 += 32){
        *(uint4*)&As[rowA*40 + koffA] = *(const uint4*)&Ap[k0];
        #pragma unroll
        for (int i=0;i<2;i++){
            int c = tid + i*256;
            int row = c >> 2, koff = (c & 3)*8;
            *(uint4*)&Bs[row*40 + koff] = *(const uint4*)&Bt[(size_t)(nbase+row)*K + k0 + koff];
        }
        __syncthreads();
        short8v af[2], bfr[4];
        #pragma unroll
        for (int mi=0;mi<2;mi++) af[mi] = *(const short8v*)&As[(wm + mi*16 + l15)*40 + quad*8];
        #pragma unroll
        for (int ni=0;ni<4;ni++) bfr[ni] = *(const short8v*)&Bs[(wn + ni*16 + l15)*40 + quad*8];
        #pragma unroll
        for (int mi=0;mi<2;mi++)
            #pragma unroll
            for (int ni=0;ni<4;ni++)
                acc[mi][ni] = __builtin_amdgcn_mfma_f32_16x16x32_bf16(af[mi], bfr[ni], acc[mi][ni], 0, 0, 0);
        __syncthreads();
    }

    // ---- vectorized epilogue via LDS transpose: two 32-row halves ----
    float* ep = (float*)ldsraw;     // 32 x 140 f32 (staging dead; loop's trailing barrier passed)
    int erow = tid >> 4;            // 0..15
    int ecc  = (tid & 15) * 8;      // 0..120
    #pragma unroll
    for (int half = 0; half < 2; ++half){
        if ((wave & 1) == half){
            #pragma unroll
            for (int mi=0;mi<2;mi++){
                #pragma unroll
                for (int ni=0;ni<4;ni++){
                    int col = wn + ni*16 + l15;
                    #pragma unroll
                    for (int reg=0;reg<4;reg++){
                        int r = mi*16 + quad*4 + reg;    // 0..31 within half
                        ep[r*140 + col] = acc[mi][ni][reg];
                    }
                }
            }
        }
        __syncthreads();
        #pragma unroll
        for (int ps=0; ps<2; ps++){
            int r = ps*16 + erow;
            int growg = mbase + half*32 + r;
            int colg = nbase + ecc;
            float4 v0 = *(const float4*)&ep[r*140 + ecc + 0];
            float4 v1 = *(const float4*)&ep[r*140 + ecc + 4];
            if (MODE == 0){
                ush8 ob;
                ob[0]=f2bu(v0.x); ob[1]=f2bu(v0.y); ob[2]=f2bu(v0.z); ob[3]=f2bu(v0.w);
                ob[4]=f2bu(v1.x); ob[5]=f2bu(v1.y); ob[6]=f2bu(v1.z); ob[7]=f2bu(v1.w);
                if (colg + 8 <= DI){
                    *(ush8*)&O1b[(size_t)growg*DI + colg] = ob;
                } else if (colg >= DI && colg + 8 <= DIP){
                    *(ush8*)&O2b[(size_t)growg*XB + (colg - DI)] = ob;
                }
                // cols >= DIP (1160..1279) are dead padding: skip
            } else {
                size_t ob1 = (size_t)growg*DM + colg;
                float4 h0 = *(const float4*)&O1[ob1];
                float4 h1 = *(const float4*)&O1[ob1+4];
                h0.x+=v0.x; h0.y+=v0.y; h0.z+=v0.z; h0.w+=v0.w;
                h1.x+=v1.x; h1.y+=v1.y; h1.z+=v1.z; h1.w+=v1.w;
                *(float4*)&O1[ob1] = h0;
                *(float4*)&O1[ob1+4] = h1;
                ush8 ob;
                ob[0]=f2bu(h0.x); ob[1]=f2bu(h0.y); ob[2]=f2bu(h0.z); ob[3]=f2bu(h0.w);
                ob[4]=f2bu(h1.x); ob[5]=f2bu(h1.y); ob[6]=f2bu(h1.z); ob[7]=f2bu(h1.w);
                *(ush8*)&O3[ob1] = ob;
            }
        }
        __syncthreads();
    }
}

// ------- conv + fused dtcum: grid.x 0..9 conv channels, block x==10 does
// the softplus/cumsum scans for the same 64-row span (2 heads per wave) -------
__global__ __launch_bounds__(256) void k_conv(const unsigned short* __restrict__ xbb,
                                              const float* __restrict__ cw,
                                              const float* __restrict__ cb,
                                              const float* __restrict__ dtb,
                                              const float* __restrict__ alog,
                                              float* __restrict__ dto,
                                              float* __restrict__ cumo,
                                              unsigned short* __restrict__ cvb){
    int tid = threadIdx.x;
    if (blockIdx.x == 10){
        int r0 = blockIdx.y*64;
        int b = r0 >> 11;            // L_ = 2048
        int l0 = r0 & (L_-1);
        int wave = tid >> 6, t = tid & 63;
        #pragma unroll
        for (int hh = 0; hh < 2; hh++){
            int h = wave + hh*4;
            float raw = u2f(xbb[(size_t)(r0 + t)*XB + CD + h]);
            float dtv = softplusf_(raw + dtb[h]);
            float A = -__expf(alog[h]);
            float s = dtv * A;
            #pragma unroll
            for (int off=1; off<64; off<<=1){
                float u = __shfl_up(s, off);
                if (t >= off) s += u;
            }
            int base = (b*NH + h)*L_ + l0 + t;
            dto[base] = dtv;
            cumo[base] = s;
        }
        return;
    }
    int c0 = (blockIdx.x*16 + (tid & 15))*4;
    int r0 = blockIdx.y*64 + (tid >> 4);
    float wA[4], wB[4], wC[4], wD[4];
    {
        float4 t0 = *(const float4*)&cw[(size_t)(c0+0)*4];
        float4 t1 = *(const float4*)&cw[(size_t)(c0+1)*4];
        float4 t2 = *(const float4*)&cw[(size_t)(c0+2)*4];
        float4 t3 = *(const float4*)&cw[(size_t)(c0+3)*4];
        wA[0]=t0.x; wA[1]=t0.y; wA[2]=t0.z; wA[3]=t0.w;
        wB[0]=t1.x; wB[1]=t1.y; wB[2]=t1.z; wB[3]=t1.w;
        wC[0]=t2.x; wC[1]=t2.y; wC[2]=t2.z; wC[3]=t2.w;
        wD[0]=t3.x; wD[1]=t3.y; wD[2]=t3.z; wD[3]=t3.w;
    }
    float4 bb = *(const float4*)&cb[c0];
    #pragma unroll
    for (int i=0;i<4;i++){
        int r = r0 + i*16;
        int l = r & (L_-1);
        float a0=bb.x, a1=bb.y, a2=bb.z, a3=bb.w;
        #pragma unroll
        for (int j=0;j<4;j++){
            if (l-3+j >= 0){
                ushort4 uv = *(const ushort4*)&xbb[(size_t)(r-3+j)*XB + c0];
                a0 += u2f(uv.x)*wA[j];
                a1 += u2f(uv.y)*wB[j];
                a2 += u2f(uv.z)*wC[j];
                a3 += u2f(uv.w)*wD[j];
            }
        }
        ushort4 ov;
        ov.x = f2bu(siluf_(a0));
        ov.y = f2bu(siluf_(a1));
        ov.z = f2bu(siluf_(a2));
        ov.w = f2bu(siluf_(a3));
        *(ushort4*)&cvb[(size_t)r*CD + c0] = ov;
    }
}

// Group-local remap: the 8 h-blocks of one (kk,b) group all get p%8==g%8,
// i.e. the same XCD -> the shared B/C tile is fetched into that L2 once.
__device__ __forceinline__ void grp_map(int p, int &kk, int &h, int &b){
    int c = p & 7, i = p >> 3;
    h = i & 7;
    int g = (i & ~7) | c;
    kk = g & (NCH-1);
    b = g >> 5;
}

// ------- passS: reads precomputed conv output (cvb) -------
__global__ __launch_bounds__(256) void k_passS(const unsigned short* __restrict__ cvb,
                                               const float* __restrict__ dt,
                                               const float* __restrict__ cum,
                                               float* __restrict__ S){
    __shared__ unsigned short Bw[64*72];
    __shared__ unsigned short Xt[64*72];
    __shared__ float sw[64];
    int kk, h, b;
    grp_map(blockIdx.x, kk, h, b);
    int tid = threadIdx.x;
    int bh = b*NH + h;
    int l0 = kk*Q_;
    if (tid < 64){
        int base = bh*L_ + l0;
        float c = cum[base + tid];
        float c63 = cum[base + 63];
        sw[tid] = dt[base + tid]*__expf(fminf(c63 - c, 0.f));
    }
    __syncthreads();
    int srow = tid >> 4, c0 = (tid & 15)*4;
    #pragma unroll
    for (int i=0;i<4;i++){
        int s = srow + i*16;
        size_t rb = ((size_t)(b*L_ + l0 + s))*CD;
        ushort4 bv = *(const ushort4*)&cvb[rb + DI + c0];
        ushort4 xv = *(const ushort4*)&cvb[rb + h*HD + c0];
        float w = sw[s];
        Bw[(c0+0)*72 + s] = f2bu(w*u2f(bv.x));
        Bw[(c0+1)*72 + s] = f2bu(w*u2f(bv.y));
        Bw[(c0+2)*72 + s] = f2bu(w*u2f(bv.z));
        Bw[(c0+3)*72 + s] = f2bu(w*u2f(bv.w));
        Xt[(c0+0)*72 + s] = xv.x;
        Xt[(c0+1)*72 + s] = xv.y;
        Xt[(c0+2)*72 + s] = xv.z;
        Xt[(c0+3)*72 + s] = xv.w;
    }
    __syncthreads();
    int wave = tid >> 6, lane = tid & 63, quad = lane >> 4, l15 = lane & 15;
    int wn = (wave & 1)*32, wp = (wave >> 1)*32;
    float4v zero4 = {0.f,0.f,0.f,0.f};
    float4v acc[2][2];
    #pragma unroll
    for (int mi=0;mi<2;mi++)
        #pragma unroll
        for (int ni=0;ni<2;ni++) acc[mi][ni] = zero4;
    #pragma unroll
    for (int k0=0;k0<64;k0+=32){
        short8v af[2], bfr[2];
        #pragma unroll
        for (int mi=0;mi<2;mi++) af[mi] = *(const short8v*)&Bw[(wn + mi*16 + l15)*72 + k0 + quad*8];
        #pragma unroll
        for (int ni=0;ni<2;ni++) bfr[ni] = *(const short8v*)&Xt[(wp + ni*16 + l15)*72 + k0 + quad*8];
        #pragma unroll
        for (int mi=0;mi<2;mi++)
            #pragma unroll
            for (int ni=0;ni<2;ni++)
                acc[mi][ni] = __builtin_amdgcn_mfma_f32_16x16x32_bf16(af[mi], bfr[ni], acc[mi][ni], 0, 0, 0);
    }
    size_t Sbase = ((size_t)bh*NCH + kk)*4096;
    #pragma unroll
    for (int mi=0;mi<2;mi++){
        #pragma unroll
        for (int ni=0;ni<2;ni++){
            int p = wp + ni*16 + l15;
            #pragma unroll
            for (int reg=0;reg<4;reg++){
                int n = wn + mi*16 + quad*4 + reg;
                S[Sbase + n*64 + p] = acc[mi][ni][reg];
            }
        }
    }
}

// ------- combine: 4-way z-split; scan in f32 registers; prefix stored as
// bf16 into the FIRST 2KB of each quarter's own 4KB f32 slot (bytes this
// block already consumed -> no cross-block overlap; intra-block overlap
// fenced by one barrier per chunk). f32 prefix store eliminated. -------
__global__ __launch_bounds__(256) void k_combine(const float* __restrict__ cum,
                                                 float* __restrict__ S,
                                                 unsigned short* __restrict__ Sb){
    int h = blockIdx.x, b = blockIdx.y, z = blockIdx.z;
    int bh = b*NH + h;
    int tid = threadIdx.x;
    float4 st = make_float4(0.f,0.f,0.f,0.f);
    size_t chunk0 = ((size_t)bh*NCH)*4096;
    int qoff = z*1024 + tid*4;
    for (int k=0;k<NCH;k++){
        size_t cb = chunk0 + (size_t)k*4096;
        float dk = __expf(fminf(cum[bh*L_ + k*Q_ + 63], 0.f));
        float4 a = *(const float4*)&S[cb + qoff];
        __syncthreads();   // all reads of chunk k before any bf16 write into it
        ushort4 pb;
        pb.x = f2bu(st.x); pb.y = f2bu(st.y); pb.z = f2bu(st.z); pb.w = f2bu(st.w);
        *(ushort4*)&Sb[2*(cb + (size_t)z*1024) + tid*4] = pb;
        st.x = a.x + dk*st.x;
        st.y = a.y + dk*st.y;
        st.z = a.z + dk*st.z;
        st.w = a.w + dk*st.w;
    }
}

// ------- finalize2: reads bf16 prefix states (Sb); Ml aliases Bs -------
__global__ __launch_bounds__(256) void k_finalize2(const unsigned short* __restrict__ cvb,
                                                   const float* __restrict__ dt,
                                                   const float* __restrict__ cum,
                                                   const float* __restrict__ Dp,
                                                   const unsigned short* __restrict__ Sb,
                                                   unsigned short* __restrict__ yB){
    __shared__ unsigned short Ct[64*72];
    __shared__ unsigned short Bs[64*72];   // aliased as Ml after GEMM1
    __shared__ unsigned short Xt[64*72];
    __shared__ unsigned short St[64*72];
    __shared__ float sdt[64], scum[64];
    unsigned short* const Ml = &Bs[0];
    int kk, h, b;
    grp_map(blockIdx.x, kk, h, b);
    int tid = threadIdx.x;
    int bh = b*NH + h;
    int l0 = kk*Q_;
    if (tid < 64){
        int base = bh*L_ + l0;
        sdt[tid] = dt[base + tid];
        scum[tid] = cum[base + tid];
    }
    int rr = tid >> 4, c0 = (tid & 15)*4;
    size_t Sbase = ((size_t)bh*NCH + kk)*4096;
    #pragma unroll
    for (int i=0;i<4;i++){
        int r = rr + i*16;
        size_t rb = ((size_t)(b*L_ + l0 + r))*CD;
        *(ushort4*)&Ct[r*72 + c0] = *(const ushort4*)&cvb[rb + DI + DS + c0];
        *(ushort4*)&Bs[r*72 + c0] = *(const ushort4*)&cvb[rb + DI + c0];
        ushort4 xv = *(const ushort4*)&cvb[rb + h*HD + c0];
        Xt[(c0+0)*72 + r] = xv.x;
        Xt[(c0+1)*72 + r] = xv.y;
        Xt[(c0+2)*72 + r] = xv.z;
        Xt[(c0+3)*72 + r] = xv.w;
        int wfull = r*64 + c0;
        int zq = wfull >> 10;
        size_t u = 2*(Sbase + ((size_t)zq<<10)) + (wfull & 1023);
        ushort4 sv = *(const ushort4*)&Sb[u];
        St[(c0+0)*72 + r] = sv.x;
        St[(c0+1)*72 + r] = sv.y;
        St[(c0+2)*72 + r] = sv.z;
        St[(c0+3)*72 + r] = sv.w;
    }
    __syncthreads();
    int wave = tid >> 6, lane = tid & 63, quad = lane >> 4, l15 = lane & 15;
    int wt2 = (wave & 1)*32, wc = (wave >> 1)*32;
    float4v zero4 = {0.f,0.f,0.f,0.f};
    {
        float4v acc[2][2];
        #pragma unroll
        for (int mi=0;mi<2;mi++)
            #pragma unroll
            for (int ni=0;ni<2;ni++) acc[mi][ni] = zero4;
        #pragma unroll
        for (int k0=0;k0<64;k0+=32){
            short8v af[2], bfr[2];
            #pragma unroll
            for (int mi=0;mi<2;mi++) af[mi] = *(const short8v*)&Ct[(wt2 + mi*16 + l15)*72 + k0 + quad*8];
            #pragma unroll
            for (int ni=0;ni<2;ni++) bfr[ni] = *(const short8v*)&Bs[(wc + ni*16 + l15)*72 + k0 + quad*8];
            #pragma unroll
            for (int mi=0;mi<2;mi++)
                #pragma unroll
                for (int ni=0;ni<2;ni++)
                    acc[mi][ni] = __builtin_amdgcn_mfma_f32_16x16x32_bf16(af[mi], bfr[ni], acc[mi][ni], 0, 0, 0);
        }
        __syncthreads();   // all waves done reading Bs before it becomes Ml
        #pragma unroll
        for (int mi=0;mi<2;mi++){
            #pragma unroll
            for (int ni=0;ni<2;ni++){
                int s = wc + ni*16 + l15;
                #pragma unroll
                for (int reg=0;reg<4;reg++){
                    int t = wt2 + mi*16 + quad*4 + reg;
                    float m = (s <= t) ? acc[mi][ni][reg]*sdt[s]*__expf(fminf(scum[t]-scum[s], 0.f)) : 0.f;
                    Ml[t*72 + s] = f2bu(m);
                }
            }
        }
    }
    __syncthreads();
    {
        float4v a1[2][2], a2[2][2];
        #pragma unroll
        for (int mi=0;mi<2;mi++)
            #pragma unroll
            for (int ni=0;ni<2;ni++){ a1[mi][ni] = zero4; a2[mi][ni] = zero4; }
        #pragma unroll
        for (int k0=0;k0<64;k0+=32){
            short8v mf[2], cf[2], xf[2], sf[2];
            #pragma unroll
            for (int mi=0;mi<2;mi++){
                mf[mi] = *(const short8v*)&Ml[(wt2 + mi*16 + l15)*72 + k0 + quad*8];
                cf[mi] = *(const short8v*)&Ct[(wt2 + mi*16 + l15)*72 + k0 + quad*8];
            }
            #pragma unroll
            for (int ni=0;ni<2;ni++){
                xf[ni] = *(const short8v*)&Xt[(wc + ni*16 + l15)*72 + k0 + quad*8];
                sf[ni] = *(const short8v*)&St[(wc + ni*16 + l15)*72 + k0 + quad*8];
            }
            #pragma unroll
            for (int mi=0;mi<2;mi++)
                #pragma unroll
                for (int ni=0;ni<2;ni++){
                    a1[mi][ni] = __builtin_amdgcn_mfma_f32_16x16x32_bf16(mf[mi], xf[ni], a1[mi][ni], 0, 0, 0);
                    a2[mi][ni] = __builtin_amdgcn_mfma_f32_16x16x32_bf16(cf[mi], sf[ni], a2[mi][ni], 0, 0, 0);
                }
        }
        float Dh = Dp[h];
        #pragma unroll
        for (int mi=0;mi<2;mi++){
            #pragma unroll
            for (int ni=0;ni<2;ni++){
                int p = wc + ni*16 + l15;
                #pragma unroll
                for (int reg=0;reg<4;reg++){
                    int t = wt2 + mi*16 + quad*4 + reg;
                    float e = __expf(fminf(scum[t], 0.f));
                    float xval = u2f(Xt[p*72 + t]);
                    yB[(size_t)(b*L_ + l0 + t)*DI + h*HD + p] =
                        f2bu(a1[mi][ni][reg] + e*a2[mi][ni][reg] + Dh*xval);
                }
            }
        }
    }
}

__global__ __launch_bounds__(256) void k_gaterms(const unsigned short* __restrict__ z,
                                                 const float* __restrict__ rw,
                                                 const unsigned short* __restrict__ yB,
                                                 unsigned short* __restrict__ ybf){
    __shared__ float red[4];
    int row = blockIdx.x;
    int tid = threadIdx.x;
    float g[2]; float ss = 0.f;
    #pragma unroll
    for (int r=0;r<2;r++){
        int d = tid + r*256;
        float zv = u2f(z[(size_t)row*DI + d]);
        float yv = u2f(yB[(size_t)row*DI + d]);
        float gv = yv * siluf_(zv);
        g[r] = gv;
        ss += gv*gv;
    }
    float tot = blockSum256(ss, red);
    float rinv = rsqrtf(tot*(1.f/512.f) + EPS_);
    #pragma unroll
    for (int r=0;r<2;r++){
        int d = tid + r*256;
        ybf[(size_t)row*DI + d] = f2bu(g[r]*rinv*rw[d]);
    }
}

// ------- fused LayerNorm + 128-row mean: 8 rows/block, one atomicAdd per
// thread into hmp (atomic ordering noise ~ulp; replaces 67MB S scratch) -----
__global__ __launch_bounds__(256) void k_lnmean(const float* __restrict__ h,
                                                const float* __restrict__ lw,
                                                const float* __restrict__ lb,
                                                float* __restrict__ hmp,
                                                int b0){
    __shared__ float red[4];
    int tid = threadIdx.x;
    int r0 = blockIdx.x*8;
    int bl = r0 >> 11;               // L_ = 2048
    int g = (r0 & (L_-1)) >> 7;      // 128-row groups
    float lwv = lw[tid], lbv = lb[tid];
    float accv = 0.f;
    for (int i=0;i<8;i++){
        int row = r0 + i;
        float v = h[(size_t)row*DM + tid];
        float mu = blockSum256(v, red)*(1.f/256.f);
        float d = v - mu;
        float var = blockSum256(d*d, red)*(1.f/256.f);
        accv += d*rsqrtf(var + EPS_)*lwv + lbv;
    }
    atomicAdd(&hmp[((size_t)(b0+bl)*16 + g)*DM + tid], accv*(1.f/2048.f));
}

__global__ __launch_bounds__(256) void k_heads(const float* __restrict__ hmp,
                                               const float* __restrict__ dw,
                                               const float* __restrict__ db,
                                               const float* __restrict__ rw,
                                               const float* __restrict__ rb,
                                               float* __restrict__ out){
    __shared__ float red[4];
    int b = blockIdx.x;
    int tid = threadIdx.x;
    float hv = 0.f;
    #pragma unroll
    for (int g=0; g<16; g++) hv += hmp[((size_t)b*16 + g)*DM + tid];
    float s0 = hv*dw[tid];
    float s1 = hv*rw[tid*3+0];
    float s2 = hv*rw[tid*3+1];
    float s3 = hv*rw[tid*3+2];
    s0 = blockSum256(s0, red);
    s1 = blockSum256(s1, red);
    s2 = blockSum256(s2, red);
    s3 = blockSum256(s3, red);
    if (tid == 0){
        out[b] = s0 + db[0];
        out[16 + b*3 + 0] = s1 + rb[0];
        out[16 + b*3 + 1] = s2 + rb[1];
        out[16 + b*3 + 2] = s3 + rb[2];
    }
}

extern "C" void kernel_launch(void* const* d_in, const int* in_sizes, int n_in,
                              void* d_out, int out_size, void* d_ws, size_t ws_size,
                              hipStream_t stream){
    static const int expSizes[NIN] = {1507328,11776,256,1187840,10240,2560,32,32,32,2048,524288,256,256,256,1,768,3};
    float* out = (float*)d_out;

    if (n_in != NIN){
        k_sentinel<<<1,64,0,stream>>>(out, 9.0e6f);
        return;
    }
    for (int i=0;i<NIN;i++){
        if (in_sizes[i] != expSizes[i]){
            k_sentinel<<<1,64,0,stream>>>(out, (float)(i+1)*1.0e5f);
            return;
        }
    }
    size_t need16 = ((size_t)SLICEOFF + 2048ull*PERROW)*4ull;
    if (ws_size < need16){
        float mb = (float)(ws_size >> 20);
        k_sentinel<<<1,64,0,stream>>>(out, 2.0e7f + mb*131072.f);
        return;
    }

    float* ws = (float*)d_ws;
    int* flags = (int*)d_ws;
    float* stg = ws + STGOFF;
    unsigned short* ipwT = (unsigned short*)(ws + WIPT);
    unsigned short* opwT = (unsigned short*)(ws + WOPT);
    float* hmp = ws + HMPOFF;

    PtrTab pt;
    for (int i=0;i<NIN;i++) pt.p[i] = d_in[i];

    k_detect<<<NIN, 256, 0, stream>>>(pt, flags);
    k_stage<<<dim3(8, NSMALL), 256, 0, stream>>>(pt, flags, stg);
    k_wip<<<dim3(NP, NL), 256, 0, stream>>>(d_in[3], flags+3, ipwT);
    k_wop<<<dim3(DM, NL), 256, 0, stream>>>(d_in[10], flags+10, opwT);
    k_zerohmp<<<B_*16*DM/256, 256, 0, stream>>>(hmp);

    const float* inp_w = stg + 0;
    const float* inp_b = stg + 11776;
    const float* cw    = stg + 12032;
    const float* cb    = stg + 22272;
    const float* dtb   = stg + 24832;
    const float* alog  = stg + 24864;
    const float* Dp    = stg + 24896;
    const float* rmsw  = stg + 24928;
    const float* lnw   = stg + 26976;
    const float* lnb   = stg + 27232;
    const float* dw    = stg + 27488;
    const float* db    = stg + 27744;
    const float* rw    = stg + 27748;
    const float* rb    = stg + 28516;

    int nsl = 1;
    while (((size_t)SLICEOFF + ((size_t)MROWS/nsl)*PERROW)*4ull > ws_size) nsl <<= 1;
    const size_t R = (size_t)MROWS / nsl;
    const int SB = B_ / nsl;

    float* base = ws + SLICEOFF;
    // Layout (floats-per-row offsets, lifetime-aliased):
    //   hbuf [0,256) f32 | hbf [256,384) bf16 | zb [384,640) bf16
    //   xbb  [640,964) bf16 (raw xBC+dt; dead after conv/dtcum) -- ybB aliases [640,896)
    //   cvb  [964,1284) bf16 (conv+SiLU; dead after finalize2) -- ybf aliases [964,1220)
    //   S    [1284,1796) f32 partials; bf16 prefixes packed into first half of
    //        each quarter slot by k_combine | dt [1796,1804) | cum [1804,1812)
    float* hbuf = base;
    unsigned short* hbf  = (unsigned short*)(base + R*256);
    unsigned short* zb   = (unsigned short*)(base + R*384);
    unsigned short* xbb  = (unsigned short*)(base + R*640);
    unsigned short* ybB  = (unsigned short*)(base + R*640);   // alias: xbb dead after conv
    unsigned short* cvb  = (unsigned short*)(base + R*964);
    unsigned short* ybf  = (unsigned short*)(base + R*964);   // alias: cvb dead after finalize2
    float* S   = base + R*1284;
    float* dt  = base + R*1796;
    float* cum = base + R*1804;

    for (int sl=0; sl<nsl; sl++){
        k_inproj<<<(int)(R/32), 256, 0, stream>>>(d_in[0], flags, (size_t)sl*R*46, inp_w, inp_b, hbuf, hbf);
        for (int li=0; li<NL; li++){
            const float* cwl = cw + li*CD*4;
            const float* cbl = cb + li*CD;
            k_mgemm<0><<<dim3(NP/128, R/64), 256, 0, stream>>>(
                hbf, ipwT + (size_t)li*NP*DM, hbuf, zb, xbb, ybf, DM);
            k_conv<<<dim3(11, (int)(R/64)), 256, 0, stream>>>(
                xbb, cwl, cbl, dtb + li*NH, alog + li*NH, dt, cum, cvb);
            k_passS<<<NCH*NH*SB, 256, 0, stream>>>(cvb, dt, cum, S);
            k_combine<<<dim3(NH,SB,4), 256, 0, stream>>>(cum, S, (unsigned short*)S);
            k_finalize2<<<NCH*NH*SB, 256, 0, stream>>>(cvb, dt, cum, Dp + li*NH,
                (const unsigned short*)S, ybB);
            k_gaterms<<<(int)R, 256, 0, stream>>>(zb, rmsw + li*DI, ybB, ybf);
            k_mgemm<1><<<dim3(DM/128, R/64), 256, 0, stream>>>(
                ybf, opwT + (size_t)li*DM*DI, hbuf, zb, xbb, hbf, DI);
        }
        k_lnmean<<<(int)(R/8), 256, 0, stream>>>(hbuf, lnw, lnb, hmp, sl*SB);
    }
    k_heads<<<B_, 256, 0, stream>>>(hmp, dw, db, rw, rb, out);
}

// Round 11
// 984.893 us; speedup vs baseline: 1.1810x; 1.0139x over previous
//
#include <hip/hip_runtime.h>
#include <hip/hip_bf16.h>
#include <math.h>

typedef __hip_bfloat16 bf16;

#define B_ 16
#define L_ 2048
#define DM 256
#define DI 512
#define NH 8
#define HD 64
#define DS 64
#define CD 640
#define DIP 1160
#define XB 648
#define NP 1280
#define NL 4
#define Q_ 64
#define NCH 32
#define MROWS (B_*L_)
#define EPS_ 1e-5f
#define NIN 17
#define NSMALL 14
#define STGOFF 32
#define WIPT 28552
#define WOPT 683912
#define HMPOFF 946056
#define SLICEOFF 1011592
#define PERROW 2004

__device__ __forceinline__ float u2f(unsigned short u){ return __uint_as_float(((unsigned)u)<<16); }
__device__ __forceinline__ unsigned short f2bu(float f){ bf16 h = __float2bfloat16(f); return *(unsigned short*)&h; }
__device__ __forceinline__ float sigmoidf_(float x){ return 1.f/(1.f+__expf(-x)); }
__device__ __forceinline__ float siluf_(float x){ return x*sigmoidf_(x); }
__device__ __forceinline__ float softplusf_(float x){ return (x>20.f)? x : log1pf(__expf(x)); }

typedef __attribute__((ext_vector_type(8))) short short8v;
typedef __attribute__((ext_vector_type(4))) float float4v;
typedef __attribute__((ext_vector_type(8))) unsigned short ush8;

__device__ const int kN17[NIN] = {1507328,11776,256,1187840,10240,2560,32,32,32,2048,524288,256,256,256,1,768,3};
__device__ const int sIdx[NSMALL] = {1,2,4,5,6,7,8,9,11,12,13,14,15,16};
__device__ const int sNum[NSMALL] = {11776,256,10240,2560,32,32,32,2048,256,256,256,1,768,3};
__device__ const int sOff[NSMALL] = {0,11776,12032,22272,24832,24864,24896,24928,26976,27232,27488,27744,27748,28516};

struct PtrTab { const void* p[NIN]; };

__global__ __launch_bounds__(64) void k_sentinel(float* out, float v){
    int t = threadIdx.x;
    out[t] = (t==0) ? v : 0.f;
}

__global__ __launch_bounds__(256) void k_detect(PtrTab t, int* flags){
    int i = blockIdx.x;
    int n = kN17[i];
    int S = n < 4096 ? n : 4096;
    const unsigned short* u = (const unsigned short*)t.p[i];
    __shared__ int big, ze, zo, so;
    if (threadIdx.x == 0){ big=0; ze=0; zo=0; so=0; }
    __syncthreads();
    int lbig=0, lze=0, lzo=0, lso=0;
    for (int j=threadIdx.x; j<S; j+=256){
        unsigned short v = u[j];
        int e = (v>>7)&0xFF;
        if (e >= 131) lbig = 1;
        int isz = ((v & 0x7FFF) == 0) ? 1 : 0;
        if (j & 1){ lso++; lzo += isz; } else { lze += isz; }
    }
    if (lbig) atomicOr(&big, 1);
    atomicAdd(&ze, lze); atomicAdd(&zo, lzo); atomicAdd(&so, lso);
    __syncthreads();
    if (threadIdx.x == 0){
        int Se = S - so;
        flags[i] = (big || (so > 0 && 4*ze >= 3*Se && 4*zo <= so)) ? 1 : 0;
    }
}

__global__ __launch_bounds__(256) void k_stage(PtrTab t, const int* __restrict__ flags,
                                               float* __restrict__ stg){
    int a = blockIdx.y;
    int idx = sIdx[a];
    int n = sNum[a];
    float* dst = stg + sOff[a];
    const void* p = t.p[idx];
    if (flags[idx]){
        const float* s = (const float*)p;
        for (int j=blockIdx.x*256+threadIdx.x; j<n; j += gridDim.x*256) dst[j] = s[j];
    } else {
        const unsigned short* s = (const unsigned short*)p;
        for (int j=blockIdx.x*256+threadIdx.x; j<n; j += gridDim.x*256) dst[j] = u2f(s[j]);
    }
}

__global__ __launch_bounds__(256) void k_wip(const void* __restrict__ src,
                                             const int* __restrict__ flag,
                                             unsigned short* __restrict__ dst){
    int n = blockIdx.x, l = blockIdx.y, k = threadIdx.x;
    unsigned short b = 0;
    if (n < DIP){
        size_t si = ((size_t)l*DM + k)*DIP + n;
        if (flag[0]) b = f2bu(((const float*)src)[si]);
        else         b = ((const unsigned short*)src)[si];
    }
    dst[((size_t)l*NP + n)*DM + k] = b;
}

__global__ __launch_bounds__(256) void k_wop(const void* __restrict__ src,
                                             const int* __restrict__ flag,
                                             unsigned short* __restrict__ dst){
    int n = blockIdx.x, l = blockIdx.y;
    for (int k = threadIdx.x; k < DI; k += 256){
        size_t si = ((size_t)l*DI + k)*DM + n;
        unsigned short b;
        if (flag[0]) b = f2bu(((const float*)src)[si]);
        else         b = ((const unsigned short*)src)[si];
        dst[((size_t)l*DM + n)*DI + k] = b;
    }
}

__global__ __launch_bounds__(256) void k_zerohmp(float* __restrict__ hmp){
    hmp[(size_t)blockIdx.x*256 + threadIdx.x] = 0.f;
}

__device__ __forceinline__ float blockSum256(float v, float* red){
    #pragma unroll
    for (int off=32; off>0; off>>=1) v += __shfl_down(v, off);
    if ((threadIdx.x & 63) == 0) red[threadIdx.x >> 6] = v;
    __syncthreads();
    float s = red[0] + red[1] + red[2] + red[3];
    __syncthreads();
    return s;
}

// ------- inproj: 32 rows per block; w read once per block, reused 32x -------
__global__ __launch_bounds__(256) void k_inproj(const void* __restrict__ x,
                                                const int* __restrict__ flags,
                                                size_t xoff,
                                                const float* __restrict__ w,
                                                const float* __restrict__ bias,
                                                float* __restrict__ h,
                                                unsigned short* __restrict__ hbf){
    __shared__ float xs[32*46];
    int row0 = blockIdx.x*32;
    int t = threadIdx.x;
    bool f32 = flags[0] != 0;
    for (int j = t; j < 32*46; j += 256){
        size_t gi = xoff + (size_t)row0*46 + j;
        xs[j] = f32 ? ((const float*)x)[gi] : u2f(((const unsigned short*)x)[gi]);
    }
    __syncthreads();
    float bv = bias[t];
    float acc[32];
    #pragma unroll
    for (int r=0;r<32;r++) acc[r] = bv;
    for (int k=0;k<46;k++){
        float wv = w[k*DM + t];
        #pragma unroll
        for (int r=0;r<32;r++) acc[r] += xs[r*46 + k]*wv;
    }
    #pragma unroll
    for (int r=0;r<32;r++){
        size_t o = (size_t)(row0 + r)*DM + t;
        h[o] = acc[r];
        hbf[o] = f2bu(acc[r]);
    }
}

// ------- mgemm: 64x128 tile, BK=64 K-slices (half the barrier rounds) with
// 72-short padded rows (144B = 9*16B: every b128 access 16B-aligned; bank
// stride 36 dwords == 4 mod 32 -> 2-way aliasing, free) + LDS-transpose
// coalesced epilogue. K accumulation order unchanged -> bit-identical. ------
template<int MODE>
__global__ __launch_bounds__(256, 4) void k_mgemm(const unsigned short* __restrict__ A,
                                                  const unsigned short* __restrict__ Bt,
                                                  float* __restrict__ O1,
                                                  unsigned short* __restrict__ O1b,
                                                  unsigned short* __restrict__ O2b,
                                                  unsigned short* __restrict__ O3,
                                                  int K){
    // LDS pool: staging As 64*72*2=9216B + Bs 128*72*2=18432B = 27648B;
    // epilogue 32*140*4=17920B reuses the same pool.
    __shared__ __align__(16) char ldsraw[27648];
    unsigned short* As = (unsigned short*)ldsraw;            // 64*72 shorts
    unsigned short* Bs = (unsigned short*)(ldsraw + 9216);   // 128*72 shorts
    int tid = threadIdx.x;
    int wave = tid >> 6, lane = tid & 63, quad = lane >> 4, l15 = lane & 15;
    // XCD-aware bijective swizzle (nwg%8==0 for all grids here).
    int p = blockIdx.y * gridDim.x + blockIdx.x;
    int nwg = gridDim.x * gridDim.y;
    int cpx = nwg >> 3;
    int logical = (p & 7) * cpx + (p >> 3);
    int by = logical / gridDim.x;
    int bx = logical - by * gridDim.x;
    int mbase = by*64, nbase = bx*128;
    int wm = (wave & 1)*32, wn = (wave >> 1)*64;
    float4v zero4 = {0.f,0.f,0.f,0.f};
    float4v acc[2][4];
    #pragma unroll
    for (int mi=0;mi<2;mi++)
        #pragma unroll
        for (int ni=0;ni<4;ni++) acc[mi][ni] = zero4;

    for (int k0 = 0; k0 < K; k0 += 64){
        // stage A: 512 uint4 chunks (2/thread); rows 0..63, 8 chunks/row
        #pragma unroll
        for (int i=0;i<2;i++){
            int c = tid + i*256;
            int row = c >> 3, koff = (c & 7)*8;
            *(uint4*)&As[row*72 + koff] = *(const uint4*)&A[(size_t)(mbase+row)*K + k0 + koff];
        }
        // stage B: 1024 uint4 chunks (4/thread); rows 0..127
        #pragma unroll
        for (int i=0;i<4;i++){
            int c = tid + i*256;
            int row = c >> 3, koff = (c & 7)*8;
            *(uint4*)&Bs[row*72 + koff] = *(const uint4*)&Bt[(size_t)(nbase+row)*K + k0 + koff];
        }
        __syncthreads();
        #pragma unroll
        for (int ks=0; ks<64; ks+=32){
            short8v af[2], bfr[4];
            #pragma unroll
            for (int mi=0;mi<2;mi++) af[mi] = *(const short8v*)&As[(wm + mi*16 + l15)*72 + ks + quad*8];
            #pragma unroll
            for (int ni=0;ni<4;ni++) bfr[ni] = *(const short8v*)&Bs[(wn + ni*16 + l15)*72 + ks + quad*8];
            #pragma unroll
            for (int mi=0;mi<2;mi++)
                #pragma unroll
                for (int ni=0;ni<4;ni++)
                    acc[mi][ni] = __builtin_amdgcn_mfma_f32_16x16x32_bf16(af[mi], bfr[ni], acc[mi][ni], 0, 0, 0);
        }
        __syncthreads();
    }

    // ---- vectorized epilogue via LDS transpose: two 32-row halves ----
    float* ep = (float*)ldsraw;     // 32 x 140 f32 (staging dead; loop's trailing barrier passed)
    int erow = tid >> 4;            // 0..15
    int ecc  = (tid & 15) * 8;      // 0..120
    #pragma unroll
    for (int half = 0; half < 2; ++half){
        if ((wave & 1) == half){
            #pragma unroll
            for (int mi=0;mi<2;mi++){
                #pragma unroll
                for (int ni=0;ni<4;ni++){
                    int col = wn + ni*16 + l15;
                    #pragma unroll
                    for (int reg=0;reg<4;reg++){
                        int r = mi*16 + quad*4 + reg;    // 0..31 within half
                        ep[r*140 + col] = acc[mi][ni][reg];
                    }
                }
            }
        }
        __syncthreads();
        #pragma unroll
        for (int ps=0; ps<2; ps++){
            int r = ps*16 + erow;
            int growg = mbase + half*32 + r;
            int colg = nbase + ecc;
            float4 v0 = *(const float4*)&ep[r*140 + ecc + 0];
            float4 v1 = *(const float4*)&ep[r*140 + ecc + 4];
            if (MODE == 0){
                ush8 ob;
                ob[0]=f2bu(v0.x); ob[1]=f2bu(v0.y); ob[2]=f2bu(v0.z); ob[3]=f2bu(v0.w);
                ob[4]=f2bu(v1.x); ob[5]=f2bu(v1.y); ob[6]=f2bu(v1.z); ob[7]=f2bu(v1.w);
                if (colg + 8 <= DI){
                    *(ush8*)&O1b[(size_t)growg*DI + colg] = ob;
                } else if (colg >= DI && colg + 8 <= DIP){
                    *(ush8*)&O2b[(size_t)growg*XB + (colg - DI)] = ob;
                }
                // cols >= DIP (1160..1279) are dead padding: skip
            } else {
                size_t ob1 = (size_t)growg*DM + colg;
                float4 h0 = *(const float4*)&O1[ob1];
                float4 h1 = *(const float4*)&O1[ob1+4];
                h0.x+=v0.x; h0.y+=v0.y; h0.z+=v0.z; h0.w+=v0.w;
                h1.x+=v1.x; h1.y+=v1.y; h1.z+=v1.z; h1.w+=v1.w;
                *(float4*)&O1[ob1] = h0;
                *(float4*)&O1[ob1+4] = h1;
                ush8 ob;
                ob[0]=f2bu(h0.x); ob[1]=f2bu(h0.y); ob[2]=f2bu(h0.z); ob[3]=f2bu(h0.w);
                ob[4]=f2bu(h1.x); ob[5]=f2bu(h1.y); ob[6]=f2bu(h1.z); ob[7]=f2bu(h1.w);
                *(ush8*)&O3[ob1] = ob;
            }
        }
        __syncthreads();
    }
}

// ------- conv + fused dtcum: grid.x 0..9 conv channels, block x==10 does
// the softplus/cumsum scans for the same 64-row span (2 heads per wave) -------
__global__ __launch_bounds__(256) void k_conv(const unsigned short* __restrict__ xbb,
                                              const float* __restrict__ cw,
                                              const float* __restrict__ cb,
                                              const float* __restrict__ dtb,
                                              const float* __restrict__ alog,
                                              float* __restrict__ dto,
                                              float* __restrict__ cumo,
                                              unsigned short* __restrict__ cvb){
    int tid = threadIdx.x;
    if (blockIdx.x == 10){
        int r0 = blockIdx.y*64;
        int b = r0 >> 11;            // L_ = 2048
        int l0 = r0 & (L_-1);
        int wave = tid >> 6, t = tid & 63;
        #pragma unroll
        for (int hh = 0; hh < 2; hh++){
            int h = wave + hh*4;
            float raw = u2f(xbb[(size_t)(r0 + t)*XB + CD + h]);
            float dtv = softplusf_(raw + dtb[h]);
            float A = -__expf(alog[h]);
            float s = dtv * A;
            #pragma unroll
            for (int off=1; off<64; off<<=1){
                float u = __shfl_up(s, off);
                if (t >= off) s += u;
            }
            int base = (b*NH + h)*L_ + l0 + t;
            dto[base] = dtv;
            cumo[base] = s;
        }
        return;
    }
    int c0 = (blockIdx.x*16 + (tid & 15))*4;
    int r0 = blockIdx.y*64 + (tid >> 4);
    float wA[4], wB[4], wC[4], wD[4];
    {
        float4 t0 = *(const float4*)&cw[(size_t)(c0+0)*4];
        float4 t1 = *(const float4*)&cw[(size_t)(c0+1)*4];
        float4 t2 = *(const float4*)&cw[(size_t)(c0+2)*4];
        float4 t3 = *(const float4*)&cw[(size_t)(c0+3)*4];
        wA[0]=t0.x; wA[1]=t0.y; wA[2]=t0.z; wA[3]=t0.w;
        wB[0]=t1.x; wB[1]=t1.y; wB[2]=t1.z; wB[3]=t1.w;
        wC[0]=t2.x; wC[1]=t2.y; wC[2]=t2.z; wC[3]=t2.w;
        wD[0]=t3.x; wD[1]=t3.y; wD[2]=t3.z; wD[3]=t3.w;
    }
    float4 bb = *(const float4*)&cb[c0];
    #pragma unroll
    for (int i=0;i<4;i++){
        int r = r0 + i*16;
        int l = r & (L_-1);
        float a0=bb.x, a1=bb.y, a2=bb.z, a3=bb.w;
        #pragma unroll
        for (int j=0;j<4;j++){
            if (l-3+j >= 0){
                ushort4 uv = *(const ushort4*)&xbb[(size_t)(r-3+j)*XB + c0];
                a0 += u2f(uv.x)*wA[j];
                a1 += u2f(uv.y)*wB[j];
                a2 += u2f(uv.z)*wC[j];
                a3 += u2f(uv.w)*wD[j];
            }
        }
        ushort4 ov;
        ov.x = f2bu(siluf_(a0));
        ov.y = f2bu(siluf_(a1));
        ov.z = f2bu(siluf_(a2));
        ov.w = f2bu(siluf_(a3));
        *(ushort4*)&cvb[(size_t)r*CD + c0] = ov;
    }
}

// Group-local remap: the 8 h-blocks of one (kk,b) group all get p%8==g%8,
// i.e. the same XCD -> the shared B/C tile is fetched into that L2 once.
__device__ __forceinline__ void grp_map(int p, int &kk, int &h, int &b){
    int c = p & 7, i = p >> 3;
    h = i & 7;
    int g = (i & ~7) | c;
    kk = g & (NCH-1);
    b = g >> 5;
}

// ------- passS: reads precomputed conv output (cvb) -------
__global__ __launch_bounds__(256) void k_passS(const unsigned short* __restrict__ cvb,
                                               const float* __restrict__ dt,
                                               const float* __restrict__ cum,
                                               float* __restrict__ S){
    __shared__ unsigned short Bw[64*72];
    __shared__ unsigned short Xt[64*72];
    __shared__ float sw[64];
    int kk, h, b;
    grp_map(blockIdx.x, kk, h, b);
    int tid = threadIdx.x;
    int bh = b*NH + h;
    int l0 = kk*Q_;
    if (tid < 64){
        int base = bh*L_ + l0;
        float c = cum[base + tid];
        float c63 = cum[base + 63];
        sw[tid] = dt[base + tid]*__expf(fminf(c63 - c, 0.f));
    }
    __syncthreads();
    int srow = tid >> 4, c0 = (tid & 15)*4;
    #pragma unroll
    for (int i=0;i<4;i++){
        int s = srow + i*16;
        size_t rb = ((size_t)(b*L_ + l0 + s))*CD;
        ushort4 bv = *(const ushort4*)&cvb[rb + DI + c0];
        ushort4 xv = *(const ushort4*)&cvb[rb + h*HD + c0];
        float w = sw[s];
        Bw[(c0+0)*72 + s] = f2bu(w*u2f(bv.x));
        Bw[(c0+1)*72 + s] = f2bu(w*u2f(bv.y));
        Bw[(c0+2)*72 + s] = f2bu(w*u2f(bv.z));
        Bw[(c0+3)*72 + s] = f2bu(w*u2f(bv.w));
        Xt[(c0+0)*72 + s] = xv.x;
        Xt[(c0+1)*72 + s] = xv.y;
        Xt[(c0+2)*72 + s] = xv.z;
        Xt[(c0+3)*72 + s] = xv.w;
    }
    __syncthreads();
    int wave = tid >> 6, lane = tid & 63, quad = lane >> 4, l15 = lane & 15;
    int wn = (wave & 1)*32, wp = (wave >> 1)*32;
    float4v zero4 = {0.f,0.f,0.f,0.f};
    float4v acc[2][2];
    #pragma unroll
    for (int mi=0;mi<2;mi++)
        #pragma unroll
        for (int ni=0;ni<2;ni++) acc[mi][ni] = zero4;
    #pragma unroll
    for (int k0=0;k0<64;k0+=32){
        short8v af[2], bfr[2];
        #pragma unroll
        for (int mi=0;mi<2;mi++) af[mi] = *(const short8v*)&Bw[(wn + mi*16 + l15)*72 + k0 + quad*8];
        #pragma unroll
        for (int ni=0;ni<2;ni++) bfr[ni] = *(const short8v*)&Xt[(wp + ni*16 + l15)*72 + k0 + quad*8];
        #pragma unroll
        for (int mi=0;mi<2;mi++)
            #pragma unroll
            for (int ni=0;ni<2;ni++)
                acc[mi][ni] = __builtin_amdgcn_mfma_f32_16x16x32_bf16(af[mi], bfr[ni], acc[mi][ni], 0, 0, 0);
    }
    size_t Sbase = ((size_t)bh*NCH + kk)*4096;
    #pragma unroll
    for (int mi=0;mi<2;mi++){
        #pragma unroll
        for (int ni=0;ni<2;ni++){
            int p = wp + ni*16 + l15;
            #pragma unroll
            for (int reg=0;reg<4;reg++){
                int n = wn + mi*16 + quad*4 + reg;
                S[Sbase + n*64 + p] = acc[mi][ni][reg];
            }
        }
    }
}

// ------- combine: 4-way z-split; scan in f32 registers; prefix stored as
// bf16 into the FIRST 2KB of each quarter's own 4KB f32 slot (bytes this
// block already consumed -> no cross-block overlap; intra-block overlap
// fenced by one barrier per chunk). f32 prefix store eliminated. -------
__global__ __launch_bounds__(256) void k_combine(const float* __restrict__ cum,
                                                 float* __restrict__ S,
                                                 unsigned short* __restrict__ Sb){
    int h = blockIdx.x, b = blockIdx.y, z = blockIdx.z;
    int bh = b*NH + h;
    int tid = threadIdx.x;
    float4 st = make_float4(0.f,0.f,0.f,0.f);
    size_t chunk0 = ((size_t)bh*NCH)*4096;
    int qoff = z*1024 + tid*4;
    for (int k=0;k<NCH;k++){
        size_t cb = chunk0 + (size_t)k*4096;
        float dk = __expf(fminf(cum[bh*L_ + k*Q_ + 63], 0.f));
        float4 a = *(const float4*)&S[cb + qoff];
        __syncthreads();   // all reads of chunk k before any bf16 write into it
        ushort4 pb;
        pb.x = f2bu(st.x); pb.y = f2bu(st.y); pb.z = f2bu(st.z); pb.w = f2bu(st.w);
        *(ushort4*)&Sb[2*(cb + (size_t)z*1024) + tid*4] = pb;
        st.x = a.x + dk*st.x;
        st.y = a.y + dk*st.y;
        st.z = a.z + dk*st.z;
        st.w = a.w + dk*st.w;
    }
}

// ------- finalize2: reads bf16 prefix states (Sb); Ml aliases Bs -------
__global__ __launch_bounds__(256) void k_finalize2(const unsigned short* __restrict__ cvb,
                                                   const float* __restrict__ dt,
                                                   const float* __restrict__ cum,
                                                   const float* __restrict__ Dp,
                                                   const unsigned short* __restrict__ Sb,
                                                   unsigned short* __restrict__ yB){
    __shared__ unsigned short Ct[64*72];
    __shared__ unsigned short Bs[64*72];   // aliased as Ml after GEMM1
    __shared__ unsigned short Xt[64*72];
    __shared__ unsigned short St[64*72];
    __shared__ float sdt[64], scum[64];
    unsigned short* const Ml = &Bs[0];
    int kk, h, b;
    grp_map(blockIdx.x, kk, h, b);
    int tid = threadIdx.x;
    int bh = b*NH + h;
    int l0 = kk*Q_;
    if (tid < 64){
        int base = bh*L_ + l0;
        sdt[tid] = dt[base + tid];
        scum[tid] = cum[base + tid];
    }
    int rr = tid >> 4, c0 = (tid & 15)*4;
    size_t Sbase = ((size_t)bh*NCH + kk)*4096;
    #pragma unroll
    for (int i=0;i<4;i++){
        int r = rr + i*16;
        size_t rb = ((size_t)(b*L_ + l0 + r))*CD;
        *(ushort4*)&Ct[r*72 + c0] = *(const ushort4*)&cvb[rb + DI + DS + c0];
        *(ushort4*)&Bs[r*72 + c0] = *(const ushort4*)&cvb[rb + DI + c0];
        ushort4 xv = *(const ushort4*)&cvb[rb + h*HD + c0];
        Xt[(c0+0)*72 + r] = xv.x;
        Xt[(c0+1)*72 + r] = xv.y;
        Xt[(c0+2)*72 + r] = xv.z;
        Xt[(c0+3)*72 + r] = xv.w;
        int wfull = r*64 + c0;
        int zq = wfull >> 10;
        size_t u = 2*(Sbase + ((size_t)zq<<10)) + (wfull & 1023);
        ushort4 sv = *(const ushort4*)&Sb[u];
        St[(c0+0)*72 + r] = sv.x;
        St[(c0+1)*72 + r] = sv.y;
        St[(c0+2)*72 + r] = sv.z;
        St[(c0+3)*72 + r] = sv.w;
    }
    __syncthreads();
    int wave = tid >> 6, lane = tid & 63, quad = lane >> 4, l15 = lane & 15;
    int wt2 = (wave & 1)*32, wc = (wave >> 1)*32;
    float4v zero4 = {0.f,0.f,0.f,0.f};
    {
        float4v acc[2][2];
        #pragma unroll
        for (int mi=0;mi<2;mi++)
            #pragma unroll
            for (int ni=0;ni<2;ni++) acc[mi][ni] = zero4;
        #pragma unroll
        for (int k0=0;k0<64;k0+=32){
            short8v af[2], bfr[2];
            #pragma unroll
            for (int mi=0;mi<2;mi++) af[mi] = *(const short8v*)&Ct[(wt2 + mi*16 + l15)*72 + k0 + quad*8];
            #pragma unroll
            for (int ni=0;ni<2;ni++) bfr[ni] = *(const short8v*)&Bs[(wc + ni*16 + l15)*72 + k0 + quad*8];
            #pragma unroll
            for (int mi=0;mi<2;mi++)
                #pragma unroll
                for (int ni=0;ni<2;ni++)
                    acc[mi][ni] = __builtin_amdgcn_mfma_f32_16x16x32_bf16(af[mi], bfr[ni], acc[mi][ni], 0, 0, 0);
        }
        __syncthreads();   // all waves done reading Bs before it becomes Ml
        #pragma unroll
        for (int mi=0;mi<2;mi++){
            #pragma unroll
            for (int ni=0;ni<2;ni++){
                int s = wc + ni*16 + l15;
                #pragma unroll
                for (int reg=0;reg<4;reg++){
                    int t = wt2 + mi*16 + quad*4 + reg;
                    float m = (s <= t) ? acc[mi][ni][reg]*sdt[s]*__expf(fminf(scum[t]-scum[s], 0.f)) : 0.f;
                    Ml[t*72 + s] = f2bu(m);
                }
            }
        }
    }
    __syncthreads();
    {
        float4v a1[2][2], a2[2][2];
        #pragma unroll
        for (int mi=0;mi<2;mi++)
            #pragma unroll
            for (int ni=0;ni<2;ni++){ a1[mi][ni] = zero4; a2[mi][ni] = zero4; }
        #pragma unroll
        for (int k0=0;k0<64;k0+=32){
            short8v mf[2], cf[2], xf[2], sf[2];
            #pragma unroll
            for (int mi=0;mi<2;mi++){
                mf[mi] = *(const short8v*)&Ml[(wt2 + mi*16 + l15)*72 + k0 + quad*8];
                cf[mi] = *(const short8v*)&Ct[(wt2 + mi*16 + l15)*72 + k0 + quad*8];
            }
            #pragma unroll
            for (int ni=0;ni<2;ni++){
                xf[ni] = *(const short8v*)&Xt[(wc + ni*16 + l15)*72 + k0 + quad*8];
                sf[ni] = *(const short8v*)&St[(wc + ni*16 + l15)*72 + k0 + quad*8];
            }
            #pragma unroll
            for (int mi=0;mi<2;mi++)
                #pragma unroll
                for (int ni=0;ni<2;ni++){
                    a1[mi][ni] = __builtin_amdgcn_mfma_f32_16x16x32_bf16(mf[mi], xf[ni], a1[mi][ni], 0, 0, 0);
                    a2[mi][ni] = __builtin_amdgcn_mfma_f32_16x16x32_bf16(cf[mi], sf[ni], a2[mi][ni], 0, 0, 0);
                }
        }
        float Dh = Dp[h];
        #pragma unroll
        for (int mi=0;mi<2;mi++){
            #pragma unroll
            for (int ni=0;ni<2;ni++){
                int p = wc + ni*16 + l15;
                #pragma unroll
                for (int reg=0;reg<4;reg++){
                    int t = wt2 + mi*16 + quad*4 + reg;
                    float e = __expf(fminf(scum[t], 0.f));
                    float xval = u2f(Xt[p*72 + t]);
                    yB[(size_t)(b*L_ + l0 + t)*DI + h*HD + p] =
                        f2bu(a1[mi][ni][reg] + e*a2[mi][ni][reg] + Dh*xval);
                }
            }
        }
    }
}

__global__ __launch_bounds__(256) void k_gaterms(const unsigned short* __restrict__ z,
                                                 const float* __restrict__ rw,
                                                 const unsigned short* __restrict__ yB,
                                                 unsigned short* __restrict__ ybf){
    __shared__ float red[4];
    int row = blockIdx.x;
    int tid = threadIdx.x;
    float g[2]; float ss = 0.f;
    #pragma unroll
    for (int r=0;r<2;r++){
        int d = tid + r*256;
        float zv = u2f(z[(size_t)row*DI + d]);
        float yv = u2f(yB[(size_t)row*DI + d]);
        float gv = yv * siluf_(zv);
        g[r] = gv;
        ss += gv*gv;
    }
    float tot = blockSum256(ss, red);
    float rinv = rsqrtf(tot*(1.f/512.f) + EPS_);
    #pragma unroll
    for (int r=0;r<2;r++){
        int d = tid + r*256;
        ybf[(size_t)row*DI + d] = f2bu(g[r]*rinv*rw[d]);
    }
}

// ------- fused LayerNorm + 128-row mean: 8 rows/block, one atomicAdd per
// thread into hmp (atomic ordering noise ~ulp; replaces 67MB S scratch) -----
__global__ __launch_bounds__(256) void k_lnmean(const float* __restrict__ h,
                                                const float* __restrict__ lw,
                                                const float* __restrict__ lb,
                                                float* __restrict__ hmp,
                                                int b0){
    __shared__ float red[4];
    int tid = threadIdx.x;
    int r0 = blockIdx.x*8;
    int bl = r0 >> 11;               // L_ = 2048
    int g = (r0 & (L_-1)) >> 7;      // 128-row groups
    float lwv = lw[tid], lbv = lb[tid];
    float accv = 0.f;
    for (int i=0;i<8;i++){
        int row = r0 + i;
        float v = h[(size_t)row*DM + tid];
        float mu = blockSum256(v, red)*(1.f/256.f);
        float d = v - mu;
        float var = blockSum256(d*d, red)*(1.f/256.f);
        accv += d*rsqrtf(var + EPS_)*lwv + lbv;
    }
    atomicAdd(&hmp[((size_t)(b0+bl)*16 + g)*DM + tid], accv*(1.f/2048.f));
}

__global__ __launch_bounds__(256) void k_heads(const float* __restrict__ hmp,
                                               const float* __restrict__ dw,
                                               const float* __restrict__ db,
                                               const float* __restrict__ rw,
                                               const float* __restrict__ rb,
                                               float* __restrict__ out){
    __shared__ float red[4];
    int b = blockIdx.x;
    int tid = threadIdx.x;
    float hv = 0.f;
    #pragma unroll
    for (int g=0; g<16; g++) hv += hmp[((size_t)b*16 + g)*DM + tid];
    float s0 = hv*dw[tid];
    float s1 = hv*rw[tid*3+0];
    float s2 = hv*rw[tid*3+1];
    float s3 = hv*rw[tid*3+2];
    s0 = blockSum256(s0, red);
    s1 = blockSum256(s1, red);
    s2 = blockSum256(s2, red);
    s3 = blockSum256(s3, red);
    if (tid == 0){
        out[b] = s0 + db[0];
        out[16 + b*3 + 0] = s1 + rb[0];
        out[16 + b*3 + 1] = s2 + rb[1];
        out[16 + b*3 + 2] = s3 + rb[2];
    }
}

extern "C" void kernel_launch(void* const* d_in, const int* in_sizes, int n_in,
                              void* d_out, int out_size, void* d_ws, size_t ws_size,
                              hipStream_t stream){
    static const int expSizes[NIN] = {1507328,11776,256,1187840,10240,2560,32,32,32,2048,524288,256,256,256,1,768,3};
    float* out = (float*)d_out;

    if (n_in != NIN){
        k_sentinel<<<1,64,0,stream>>>(out, 9.0e6f);
        return;
    }
    for (int i=0;i<NIN;i++){
        if (in_sizes[i] != expSizes[i]){
            k_sentinel<<<1,64,0,stream>>>(out, (float)(i+1)*1.0e5f);
            return;
        }
    }
    size_t need16 = ((size_t)SLICEOFF + 2048ull*PERROW)*4ull;
    if (ws_size < need16){
        float mb = (float)(ws_size >> 20);
        k_sentinel<<<1,64,0,stream>>>(out, 2.0e7f + mb*131072.f);
        return;
    }

    float* ws = (float*)d_ws;
    int* flags = (int*)d_ws;
    float* stg = ws + STGOFF;
    unsigned short* ipwT = (unsigned short*)(ws + WIPT);
    unsigned short* opwT = (unsigned short*)(ws + WOPT);
    float* hmp = ws + HMPOFF;

    PtrTab pt;
    for (int i=0;i<NIN;i++) pt.p[i] = d_in[i];

    k_detect<<<NIN, 256, 0, stream>>>(pt, flags);
    k_stage<<<dim3(8, NSMALL), 256, 0, stream>>>(pt, flags, stg);
    k_wip<<<dim3(NP, NL), 256, 0, stream>>>(d_in[3], flags+3, ipwT);
    k_wop<<<dim3(DM, NL), 256, 0, stream>>>(d_in[10], flags+10, opwT);
    k_zerohmp<<<B_*16*DM/256, 256, 0, stream>>>(hmp);

    const float* inp_w = stg + 0;
    const float* inp_b = stg + 11776;
    const float* cw    = stg + 12032;
    const float* cb    = stg + 22272;
    const float* dtb   = stg + 24832;
    const float* alog  = stg + 24864;
    const float* Dp    = stg + 24896;
    const float* rmsw  = stg + 24928;
    const float* lnw   = stg + 26976;
    const float* lnb   = stg + 27232;
    const float* dw    = stg + 27488;
    const float* db    = stg + 27744;
    const float* rw    = stg + 27748;
    const float* rb    = stg + 28516;

    int nsl = 1;
    while (((size_t)SLICEOFF + ((size_t)MROWS/nsl)*PERROW)*4ull > ws_size) nsl <<= 1;
    const size_t R = (size_t)MROWS / nsl;
    const int SB = B_ / nsl;

    float* base = ws + SLICEOFF;
    // Layout (floats-per-row offsets, lifetime-aliased):
    //   hbuf [0,256) f32 | hbf [256,384) bf16 | zb [384,640) bf16
    //   xbb  [640,964) bf16 (raw xBC+dt; dead after conv/dtcum) -- ybB aliases [640,896)
    //   cvb  [964,1284) bf16 (conv+SiLU; dead after finalize2) -- ybf aliases [964,1220)
    //   S    [1284,1796) f32 partials; bf16 prefixes packed into first half of
    //        each quarter slot by k_combine | dt [1796,1804) | cum [1804,1812)
    float* hbuf = base;
    unsigned short* hbf  = (unsigned short*)(base + R*256);
    unsigned short* zb   = (unsigned short*)(base + R*384);
    unsigned short* xbb  = (unsigned short*)(base + R*640);
    unsigned short* ybB  = (unsigned short*)(base + R*640);   // alias: xbb dead after conv
    unsigned short* cvb  = (unsigned short*)(base + R*964);
    unsigned short* ybf  = (unsigned short*)(base + R*964);   // alias: cvb dead after finalize2
    float* S   = base + R*1284;
    float* dt  = base + R*1796;
    float* cum = base + R*1804;

    for (int sl=0; sl<nsl; sl++){
        k_inproj<<<(int)(R/32), 256, 0, stream>>>(d_in[0], flags, (size_t)sl*R*46, inp_w, inp_b, hbuf, hbf);
        for (int li=0; li<NL; li++){
            const float* cwl = cw + li*CD*4;
            const float* cbl = cb + li*CD;
            k_mgemm<0><<<dim3(NP/128, R/64), 256, 0, stream>>>(
                hbf, ipwT + (size_t)li*NP*DM, hbuf, zb, xbb, ybf, DM);
            k_conv<<<dim3(11, (int)(R/64)), 256, 0, stream>>>(
                xbb, cwl, cbl, dtb + li*NH, alog + li*NH, dt, cum, cvb);
            k_passS<<<NCH*NH*SB, 256, 0, stream>>>(cvb, dt, cum, S);
            k_combine<<<dim3(NH,SB,4), 256, 0, stream>>>(cum, S, (unsigned short*)S);
            k_finalize2<<<NCH*NH*SB, 256, 0, stream>>>(cvb, dt, cum, Dp + li*NH,
                (const unsigned short*)S, ybB);
            k_gaterms<<<(int)R, 256, 0, stream>>>(zb, rmsw + li*DI, ybB, ybf);
            k_mgemm<1><<<dim3(DM/128, R/64), 256, 0, stream>>>(
                ybf, opwT + (size_t)li*DM*DI, hbuf, zb, xbb, hbf, DI);
        }
        k_lnmean<<<(int)(R/8), 256, 0, stream>>>(hbuf, lnw, lnb, hmp, sl*SB);
    }
    k_heads<<<B_, 256, 0, stream>>>(hmp, dw, db, rw, rb, out);
}